// Round 1
// baseline (3985.338 us; speedup 1.0000x reference)
//
#include <hip/hip_runtime.h>

// Problem dims
constexpr int Bb  = 64;      // batch
constexpr int Tt  = 1024;    // time
constexpr int Dd  = 288;     // padded input feature dim
constexpr int Ss  = 256;     // STATE_DIM
constexpr int ALa = 16;      // ACT_LEN
constexpr int Ll  = 256;     // LATENT
constexpr int Ee  = 512;     // ENC
constexpr int CC  = 32;      // scan chunk length
constexpr int NCh = 32;      // number of chunks (CC*NCh == Tt)
constexpr int RT  = 8;       // batch rows per scan workgroup
constexpr int DEC_CHUNKS = 8;       // decoder row-chunks (ws economy)
constexpr int DEC_ROWS = (Bb*Tt)/DEC_CHUNKS;  // 8192 rows per chunk

#define LKY(v) ((v) >= 0.f ? (v) : 0.01f*(v))

// ---------------------------------------------------------------------------
// Small dense layer for the encoder (only t=0 rows are ever used by the scan!)
// one block per batch row; weights streamed from L2.
// ---------------------------------------------------------------------------
__global__ __launch_bounds__(256) void enc_dense(
    const float* __restrict__ xin, int xstride,
    const float* __restrict__ W, const float* __restrict__ bias,
    float* __restrict__ out, int K, int N, int act)
{
  int b = blockIdx.x, tid = threadIdx.x;
  __shared__ float x[512];
  for (int k = tid; k < K; k += 256) x[k] = xin[(long)b*xstride + k];
  __syncthreads();
  for (int j = tid; j < N; j += 256){
    float acc = bias[j];
    #pragma unroll 4
    for (int k = 0; k < K; ++k) acc = fmaf(x[k], W[k*N + j], acc);
    out[b*N + j] = act ? LKY(acc) : acc;
  }
}

// ---------------------------------------------------------------------------
// 256x256 matrix squaring (for A^32 via 5 squarings). One block per row.
// ---------------------------------------------------------------------------
__global__ __launch_bounds__(256) void matsq(
    const float* __restrict__ Msrc, float* __restrict__ Mdst)
{
  int i = blockIdx.x, j = threadIdx.x;
  __shared__ float row[256];
  row[j] = Msrc[i*256 + j];
  __syncthreads();
  float acc = 0.f;
  #pragma unroll 4
  for (int k = 0; k < 256; ++k) acc = fmaf(row[k], Msrc[k*256 + j], acc);
  Mdst[i*256 + j] = acc;
}

// ---------------------------------------------------------------------------
// Scan over one chunk of CC steps for RT batch rows.
// with_init==0: zero-init local scan, store only final state to wend.
// with_init==1: init from inits[chunk], write every z[t] to zout (d_out).
// State kept transposed in LDS: sT[k][b] (pad +1 breaks write conflicts).
// Thread (ty=row, tx=col-group of 8): 8 outputs, A row read as 2x float4.
// ---------------------------------------------------------------------------
__global__ __launch_bounds__(256) void scan_chunk(
    const float* __restrict__ in0, const float* __restrict__ Bw,
    const float* __restrict__ Aw, const float* __restrict__ inits,
    float* __restrict__ wend, float* __restrict__ zout, int with_init)
{
  int chunk = blockIdx.x, b0 = blockIdx.y * RT;
  int tid = threadIdx.x;
  int tx = tid & 31, ty = tid >> 5;   // ty: batch row 0..7, tx: col group
  int c0 = tx * 8;
  __shared__ float sT[Ll][RT+1];
  __shared__ float ubuf[RT][ALa];

  float4 n0, n1;
  if (with_init){
    const float* ip = &inits[((chunk*Bb) + b0 + ty)*Ll + c0];
    n0 = *(const float4*)ip; n1 = *(const float4*)(ip+4);
  } else {
    n0 = make_float4(0.f,0.f,0.f,0.f); n1 = make_float4(0.f,0.f,0.f,0.f);
  }
  sT[c0+0][ty]=n0.x; sT[c0+1][ty]=n0.y; sT[c0+2][ty]=n0.z; sT[c0+3][ty]=n0.w;
  sT[c0+4][ty]=n1.x; sT[c0+5][ty]=n1.y; sT[c0+6][ty]=n1.z; sT[c0+7][ty]=n1.w;

  const float4* A4 = (const float4*)Aw;
  const float4* B4 = (const float4*)Bw;

  for (int tt = 0; tt < CC; ++tt){
    int t = chunk*CC + tt;
    if (tid < RT*ALa){
      int ub = tid >> 4, uk = tid & 15;
      ubuf[ub][uk] = in0[(long)(b0+ub)*(Tt*Dd) + t*Dd + (Ss+ALa) + uk];
    }
    __syncthreads();  // u visible; previous iteration's sT writes visible

    // Bu contribution
    float4 a0c = make_float4(0.f,0.f,0.f,0.f), a1c = make_float4(0.f,0.f,0.f,0.f);
    #pragma unroll
    for (int k = 0; k < ALa; ++k){
      float uv = ubuf[ty][k];
      float4 w0 = B4[(k*Ll + c0) >> 2];
      float4 w1 = B4[((k*Ll + c0) >> 2) + 1];
      a0c.x = fmaf(uv, w0.x, a0c.x); a0c.y = fmaf(uv, w0.y, a0c.y);
      a0c.z = fmaf(uv, w0.z, a0c.z); a0c.w = fmaf(uv, w0.w, a0c.w);
      a1c.x = fmaf(uv, w1.x, a1c.x); a1c.y = fmaf(uv, w1.y, a1c.y);
      a1c.z = fmaf(uv, w1.z, a1c.z); a1c.w = fmaf(uv, w1.w, a1c.w);
    }
    // s @ A contribution
    #pragma unroll 4
    for (int k = 0; k < Ll; ++k){
      float sv = sT[k][ty];
      float4 a0 = A4[(k*Ll + c0) >> 2];
      float4 a1 = A4[((k*Ll + c0) >> 2) + 1];
      a0c.x = fmaf(sv, a0.x, a0c.x); a0c.y = fmaf(sv, a0.y, a0c.y);
      a0c.z = fmaf(sv, a0.z, a0c.z); a0c.w = fmaf(sv, a0.w, a0c.w);
      a1c.x = fmaf(sv, a1.x, a1c.x); a1c.y = fmaf(sv, a1.y, a1c.y);
      a1c.z = fmaf(sv, a1.z, a1c.z); a1c.w = fmaf(sv, a1.w, a1c.w);
    }
    __syncthreads();  // all reads of old state done before overwrite
    n0 = a0c; n1 = a1c;
    sT[c0+0][ty]=n0.x; sT[c0+1][ty]=n0.y; sT[c0+2][ty]=n0.z; sT[c0+3][ty]=n0.w;
    sT[c0+4][ty]=n1.x; sT[c0+5][ty]=n1.y; sT[c0+6][ty]=n1.z; sT[c0+7][ty]=n1.w;
    if (with_init){
      float4* zp = (float4*)&zout[((long)(b0+ty)*Tt + t)*Ll + c0];
      zp[0] = n0; zp[1] = n1;
    }
  }
  if (!with_init){
    float* wp = &wend[((chunk*Bb) + b0 + ty)*Ll + c0];
    *(float4*)wp = n0; *(float4*)(wp+4) = n1;
  }
}

// ---------------------------------------------------------------------------
// Chunk-boundary sweep: inits[j+1] = inits[j] @ A32 + wend[j].
// One block per batch row (rows independent) -> no grid sync needed.
// ---------------------------------------------------------------------------
__global__ __launch_bounds__(256) void scan_pass2(
    const float* __restrict__ A32, const float* __restrict__ wend,
    float* __restrict__ inits)
{
  int b = blockIdx.x, tid = threadIdx.x;
  __shared__ float cur[256];
  cur[tid] = inits[b*256 + tid];   // inits[0] == z0 (encoder output)
  __syncthreads();
  for (int j = 0; j < NCh-1; ++j){
    float acc = wend[((j*Bb) + b)*256 + tid];
    #pragma unroll 4
    for (int k = 0; k < 256; ++k) acc = fmaf(cur[k], A32[k*256 + tid], acc);
    __syncthreads();
    cur[tid] = acc;
    inits[(((j+1)*Bb) + b)*256 + tid] = acc;
    __syncthreads();
  }
}

// ---------------------------------------------------------------------------
// Decoder GEMM: Y[M x N] = act(X[M x K] @ W[K x N] + bias), row-major.
// 128x128 block tile, BK=16, 256 threads, 8x8 register micro-tile.
// ---------------------------------------------------------------------------
__global__ __launch_bounds__(256) void gemm_bias_act(
    const float* __restrict__ X, const float* __restrict__ W,
    const float* __restrict__ bias, float* __restrict__ Y,
    int K, int N, int act)
{
  __shared__ float Xs[16][132];
  __shared__ float Ws[16][132];
  int tid = threadIdx.x;
  int tx = tid & 15, ty = tid >> 4;
  long row0 = (long)blockIdx.y * 128;
  int col0 = blockIdx.x * 128;

  float acc[8][8];
  #pragma unroll
  for (int r = 0; r < 8; ++r)
    #pragma unroll
    for (int c = 0; c < 8; ++c) acc[r][c] = 0.f;

  for (int kt = 0; kt < K; kt += 16){
    #pragma unroll
    for (int i = 0; i < 2; ++i){
      int f = tid + i*256;             // 512 float4 slots
      int m  = f >> 2, k4 = (f & 3) << 2;
      float4 v = *(const float4*)&X[(row0 + m)*K + kt + k4];
      Xs[k4+0][m] = v.x; Xs[k4+1][m] = v.y; Xs[k4+2][m] = v.z; Xs[k4+3][m] = v.w;
      int wk = f >> 5, wn = (f & 31) << 2;
      *(float4*)&Ws[wk][wn] = *(const float4*)&W[(long)(kt + wk)*N + col0 + wn];
    }
    __syncthreads();
    #pragma unroll
    for (int kk = 0; kk < 16; ++kk){
      float a[8], bb[8];
      *(float4*)&a[0]  = *(const float4*)&Xs[kk][ty*8];
      *(float4*)&a[4]  = *(const float4*)&Xs[kk][ty*8+4];
      *(float4*)&bb[0] = *(const float4*)&Ws[kk][tx*8];
      *(float4*)&bb[4] = *(const float4*)&Ws[kk][tx*8+4];
      #pragma unroll
      for (int r = 0; r < 8; ++r)
        #pragma unroll
        for (int c = 0; c < 8; ++c) acc[r][c] = fmaf(a[r], bb[c], acc[r][c]);
    }
    __syncthreads();
  }

  #pragma unroll
  for (int r = 0; r < 8; ++r){
    long m = row0 + ty*8 + r;
    #pragma unroll
    for (int c = 0; c < 8; c += 4){
      int n = col0 + tx*8 + c;
      float4 bv = *(const float4*)&bias[n];
      float4 o;
      o.x = acc[r][c+0] + bv.x; o.y = acc[r][c+1] + bv.y;
      o.z = acc[r][c+2] + bv.z; o.w = acc[r][c+3] + bv.w;
      if (act){ o.x = LKY(o.x); o.y = LKY(o.y); o.z = LKY(o.z); o.w = LKY(o.w); }
      *(float4*)&Y[m*N + n] = o;
    }
  }
}

// ---------------------------------------------------------------------------
extern "C" void kernel_launch(void* const* d_in, const int* in_sizes, int n_in,
                              void* d_out, int out_size, void* d_ws, size_t ws_size,
                              hipStream_t stream) {
  const float* in0    = (const float*)d_in[0];
  const float* enc_w1 = (const float*)d_in[1];
  const float* enc_b1 = (const float*)d_in[2];
  const float* enc_w2 = (const float*)d_in[3];
  const float* enc_b2 = (const float*)d_in[4];
  const float* enc_w3 = (const float*)d_in[5];
  const float* enc_b3 = (const float*)d_in[6];
  const float* A_w    = (const float*)d_in[7];
  const float* B_w    = (const float*)d_in[8];
  const float* dec_w1 = (const float*)d_in[9];
  const float* dec_b1 = (const float*)d_in[10];
  const float* dec_w2 = (const float*)d_in[11];
  const float* dec_b2 = (const float*)d_in[12];
  const float* dec_w3 = (const float*)d_in[13];
  const float* dec_b3 = (const float*)d_in[14];
  float* out = (float*)d_out;

  // workspace layout (floats); total 9,633,792 floats = 38.5 MB
  float* ws    = (float*)d_ws;
  float* h1enc = ws;                  // 64*512
  float* h2enc = ws + 32768;          // 64*512
  float* P1    = ws + 65536;          // 256*256
  float* P2    = ws + 131072;         // 256*256
  float* wend  = ws + 196608;         // 32*64*256
  float* inits = ws + 720896;         // 32*64*256 (inits[0] = z0)
  float* h1    = ws + 1245184;        // 8192*512
  float* h2    = ws + 5439488;        // 8192*512

  // Encoder: ONLY t=0 feeds the scan; everything else is dead code in the ref.
  enc_dense<<<64, 256, 0, stream>>>(in0, Tt*Dd, enc_w1, enc_b1, h1enc, 256, 512, 1);
  enc_dense<<<64, 256, 0, stream>>>(h1enc, 512, enc_w2, enc_b2, h2enc, 512, 512, 1);
  enc_dense<<<64, 256, 0, stream>>>(h2enc, 512, enc_w3, enc_b3, inits, 512, 256, 1);

  // A^32 by repeated squaring
  matsq<<<256, 256, 0, stream>>>(A_w, P1);   // A^2
  matsq<<<256, 256, 0, stream>>>(P1, P2);    // A^4
  matsq<<<256, 256, 0, stream>>>(P2, P1);    // A^8
  matsq<<<256, 256, 0, stream>>>(P1, P2);    // A^16
  matsq<<<256, 256, 0, stream>>>(P2, P1);    // A^32

  // Pass 1: local zero-init scans -> chunk end states
  scan_chunk<<<dim3(NCh, Bb/RT), 256, 0, stream>>>(in0, B_w, A_w, nullptr, wend, nullptr, 0);
  // Pass 2: chunk-boundary recurrence (64 independent batch rows)
  scan_pass2<<<64, 256, 0, stream>>>(P1, wend, inits);
  // Pass 3: replay chunks with true inits; z goes straight into d_out (reused
  // as scratch; decoder L3 overwrites each row-chunk only after L1 read it).
  scan_chunk<<<dim3(NCh, Bb/RT), 256, 0, stream>>>(in0, B_w, A_w, inits, nullptr, out, 1);

  // Decoder: 3-layer MLP on 65536 rows, row-chunked to bound ws
  for (int rc = 0; rc < DEC_CHUNKS; ++rc){
    const float* zc = out + (long)rc*DEC_ROWS*Ll;
    float* oc       = out + (long)rc*DEC_ROWS*Ll;
    gemm_bias_act<<<dim3(Ee/128, DEC_ROWS/128), 256, 0, stream>>>(zc, dec_w1, dec_b1, h1, Ll, Ee, 1);
    gemm_bias_act<<<dim3(Ee/128, DEC_ROWS/128), 256, 0, stream>>>(h1, dec_w2, dec_b2, h2, Ee, Ee, 1);
    gemm_bias_act<<<dim3(Ss/128, DEC_ROWS/128), 256, 0, stream>>>(h2, dec_w3, dec_b3, oc, Ee, Ss, 0);
  }
}

// Round 2
// 2337.529 us; speedup vs baseline: 1.7049x; 1.7049x over previous
//
#include <hip/hip_runtime.h>

// Problem dims
constexpr int Bb  = 64;      // batch
constexpr int Tt  = 1024;    // time
constexpr int Dd  = 288;     // padded input feature dim
constexpr int Ss  = 256;     // STATE_DIM
constexpr int ALa = 16;      // ACT_LEN
constexpr int Ll  = 256;     // LATENT
constexpr int Ee  = 512;     // ENC
constexpr int CC  = 8;       // scan chunk length
constexpr int NCh = 128;     // number of chunks (CC*NCh == Tt)
constexpr int RT  = 16;      // batch rows per scan workgroup (2 per thread)
constexpr int DEC_CHUNKS = 8;
constexpr int DEC_ROWS = (Bb*Tt)/DEC_CHUNKS;  // 8192 rows per chunk

#define LKY(v) ((v) >= 0.f ? (v) : 0.01f*(v))

// ---------------------------------------------------------------------------
// Small dense layer for the encoder (only t=0 rows feed the scan).
// ---------------------------------------------------------------------------
__global__ __launch_bounds__(256) void enc_dense(
    const float* __restrict__ xin, int xstride,
    const float* __restrict__ W, const float* __restrict__ bias,
    float* __restrict__ out, int K, int N, int act)
{
  int b = blockIdx.x, tid = threadIdx.x;
  __shared__ float x[512];
  for (int k = tid; k < K; k += 256) x[k] = xin[(long)b*xstride + k];
  __syncthreads();
  for (int j = tid; j < N; j += 256){
    float acc = bias[j];
    #pragma unroll 4
    for (int k = 0; k < K; ++k) acc = fmaf(x[k], W[k*N + j], acc);
    out[b*N + j] = act ? LKY(acc) : acc;
  }
}

// ---------------------------------------------------------------------------
// 256x256 matrix squaring (A^2, A^4, A^8). One block per row.
// ---------------------------------------------------------------------------
__global__ __launch_bounds__(256) void matsq(
    const float* __restrict__ Msrc, float* __restrict__ Mdst)
{
  int i = blockIdx.x, j = threadIdx.x;
  __shared__ float row[256];
  row[j] = Msrc[i*256 + j];
  __syncthreads();
  float p0=0.f,p1=0.f,p2=0.f,p3=0.f;
  #pragma unroll 8
  for (int k = 0; k < 256; k += 4){
    p0 = fmaf(row[k+0], Msrc[(k+0)*256 + j], p0);
    p1 = fmaf(row[k+1], Msrc[(k+1)*256 + j], p1);
    p2 = fmaf(row[k+2], Msrc[(k+2)*256 + j], p2);
    p3 = fmaf(row[k+3], Msrc[(k+3)*256 + j], p3);
  }
  Mdst[i*256 + j] = (p0+p1)+(p2+p3);
}

// ---------------------------------------------------------------------------
// Scan over one chunk of CC steps for RT=16 batch rows (2 rows per thread).
// with_init==0: zero-init local scan, store only final state to wend.
// with_init==1: init from inits[chunk], write every z[t] to zout (d_out).
// State transposed in LDS: sT[k][r], r in 0..15.  u prefetched across steps.
// ---------------------------------------------------------------------------
__global__ __launch_bounds__(256) void scan_chunk(
    const float* __restrict__ in0, const float* __restrict__ Bw,
    const float* __restrict__ Aw, const float* __restrict__ inits,
    float* __restrict__ wend, float* __restrict__ zout, int with_init)
{
  int chunk = blockIdx.x, b0 = blockIdx.y * RT;
  int tid = threadIdx.x;
  int tx = tid & 31, ty = tid >> 5;   // tx: col group (8 cols), ty: 0..7
  int r0 = ty, r1 = ty + 8;           // two batch rows per thread
  int c0 = tx * 8;
  __shared__ float sT[Ll][RT+1];
  __shared__ float ubuf[RT][ALa];

  // state registers: rows r0,r1 x cols c0..c0+7
  float4 s0a, s0b, s1a, s1b;
  if (with_init){
    const float* ip0 = &inits[((chunk*Bb) + b0 + r0)*Ll + c0];
    const float* ip1 = &inits[((chunk*Bb) + b0 + r1)*Ll + c0];
    s0a = *(const float4*)ip0; s0b = *(const float4*)(ip0+4);
    s1a = *(const float4*)ip1; s1b = *(const float4*)(ip1+4);
  } else {
    s0a = make_float4(0,0,0,0); s0b = s0a; s1a = s0a; s1b = s0a;
  }
  sT[c0+0][r0]=s0a.x; sT[c0+1][r0]=s0a.y; sT[c0+2][r0]=s0a.z; sT[c0+3][r0]=s0a.w;
  sT[c0+4][r0]=s0b.x; sT[c0+5][r0]=s0b.y; sT[c0+6][r0]=s0b.z; sT[c0+7][r0]=s0b.w;
  sT[c0+0][r1]=s1a.x; sT[c0+1][r1]=s1a.y; sT[c0+2][r1]=s1a.z; sT[c0+3][r1]=s1a.w;
  sT[c0+4][r1]=s1b.x; sT[c0+5][r1]=s1b.y; sT[c0+6][r1]=s1b.z; sT[c0+7][r1]=s1b.w;

  const float4* A4 = (const float4*)Aw;
  const float4* B4 = (const float4*)Bw;

  // u prefetch: each thread owns one (row, k) element per step
  int ub = tid >> 4, uk = tid & 15;
  const float* uptr = in0 + (long)(b0 + ub)*(Tt*Dd) + (Ss + ALa) + uk;
  float uv = uptr[(long)(chunk*CC)*Dd];

  for (int tt = 0; tt < CC; ++tt){
    int t = chunk*CC + tt;
    ubuf[ub][uk] = uv;
    __syncthreads();  // ubuf + previous sT writes visible
    if (tt + 1 < CC) uv = uptr[(long)(t+1)*Dd];   // consumed next iter (hidden)

    float4 c0a = make_float4(0,0,0,0), c0b = c0a, c1a = c0a, c1b = c0a;
    // Bu contribution (K=16)
    #pragma unroll
    for (int k = 0; k < ALa; ++k){
      float u0 = ubuf[r0][k], u1 = ubuf[r1][k];
      float4 w0 = B4[k*64 + (tx<<1)];
      float4 w1 = B4[k*64 + (tx<<1) + 1];
      c0a.x=fmaf(u0,w0.x,c0a.x); c0a.y=fmaf(u0,w0.y,c0a.y); c0a.z=fmaf(u0,w0.z,c0a.z); c0a.w=fmaf(u0,w0.w,c0a.w);
      c0b.x=fmaf(u0,w1.x,c0b.x); c0b.y=fmaf(u0,w1.y,c0b.y); c0b.z=fmaf(u0,w1.z,c0b.z); c0b.w=fmaf(u0,w1.w,c0b.w);
      c1a.x=fmaf(u1,w0.x,c1a.x); c1a.y=fmaf(u1,w0.y,c1a.y); c1a.z=fmaf(u1,w0.z,c1a.z); c1a.w=fmaf(u1,w0.w,c1a.w);
      c1b.x=fmaf(u1,w1.x,c1b.x); c1b.y=fmaf(u1,w1.y,c1b.y); c1b.z=fmaf(u1,w1.z,c1b.z); c1b.w=fmaf(u1,w1.w,c1b.w);
    }
    // s @ A contribution (K=256), 16 independent FMA chains
    #pragma unroll 4
    for (int k = 0; k < Ll; ++k){
      float v0 = sT[k][r0], v1 = sT[k][r1];
      float4 a0 = A4[k*64 + (tx<<1)];
      float4 a1 = A4[k*64 + (tx<<1) + 1];
      c0a.x=fmaf(v0,a0.x,c0a.x); c0a.y=fmaf(v0,a0.y,c0a.y); c0a.z=fmaf(v0,a0.z,c0a.z); c0a.w=fmaf(v0,a0.w,c0a.w);
      c0b.x=fmaf(v0,a1.x,c0b.x); c0b.y=fmaf(v0,a1.y,c0b.y); c0b.z=fmaf(v0,a1.z,c0b.z); c0b.w=fmaf(v0,a1.w,c0b.w);
      c1a.x=fmaf(v1,a0.x,c1a.x); c1a.y=fmaf(v1,a0.y,c1a.y); c1a.z=fmaf(v1,a0.z,c1a.z); c1a.w=fmaf(v1,a0.w,c1a.w);
      c1b.x=fmaf(v1,a1.x,c1b.x); c1b.y=fmaf(v1,a1.y,c1b.y); c1b.z=fmaf(v1,a1.z,c1b.z); c1b.w=fmaf(v1,a1.w,c1b.w);
    }
    __syncthreads();  // all reads of old state done before overwrite
    s0a=c0a; s0b=c0b; s1a=c1a; s1b=c1b;
    sT[c0+0][r0]=s0a.x; sT[c0+1][r0]=s0a.y; sT[c0+2][r0]=s0a.z; sT[c0+3][r0]=s0a.w;
    sT[c0+4][r0]=s0b.x; sT[c0+5][r0]=s0b.y; sT[c0+6][r0]=s0b.z; sT[c0+7][r0]=s0b.w;
    sT[c0+0][r1]=s1a.x; sT[c0+1][r1]=s1a.y; sT[c0+2][r1]=s1a.z; sT[c0+3][r1]=s1a.w;
    sT[c0+4][r1]=s1b.x; sT[c0+5][r1]=s1b.y; sT[c0+6][r1]=s1b.z; sT[c0+7][r1]=s1b.w;
    if (with_init){
      float4* zp0 = (float4*)&zout[((long)(b0+r0)*Tt + t)*Ll + c0];
      float4* zp1 = (float4*)&zout[((long)(b0+r1)*Tt + t)*Ll + c0];
      zp0[0] = s0a; zp0[1] = s0b;
      zp1[0] = s1a; zp1[1] = s1b;
    }
  }
  if (!with_init){
    float* w0 = &wend[((chunk*Bb) + b0 + r0)*Ll + c0];
    float* w1 = &wend[((chunk*Bb) + b0 + r1)*Ll + c0];
    *(float4*)w0 = s0a; *(float4*)(w0+4) = s0b;
    *(float4*)w1 = s1a; *(float4*)(w1+4) = s1b;
  }
}

// ---------------------------------------------------------------------------
// Chunk-boundary sweep: inits[j+1] = inits[j] @ A8 + wend[j].
// One block per batch row. 8 partial-sum chains, deep load pipelining.
// ---------------------------------------------------------------------------
__global__ __launch_bounds__(256) void scan_pass2(
    const float* __restrict__ A8, const float* __restrict__ wend,
    float* __restrict__ inits)
{
  int b = blockIdx.x, tid = threadIdx.x;
  __shared__ float cur[256];
  cur[tid] = inits[b*256 + tid];   // inits[0] == z0 (encoder output)
  __syncthreads();
  for (int j = 0; j < NCh-1; ++j){
    float p[8] = {0,0,0,0,0,0,0,0};
    #pragma unroll 4
    for (int k = 0; k < 256; k += 8){
      #pragma unroll
      for (int q = 0; q < 8; ++q)
        p[q] = fmaf(cur[k+q], A8[(k+q)*256 + tid], p[q]);
    }
    float acc = wend[((j*Bb) + b)*256 + tid]
              + (((p[0]+p[1])+(p[2]+p[3])) + ((p[4]+p[5])+(p[6]+p[7])));
    __syncthreads();
    cur[tid] = acc;
    inits[(((j+1)*Bb) + b)*256 + tid] = acc;
    __syncthreads();
  }
}

// ---------------------------------------------------------------------------
// Decoder GEMM: Y[M x N] = act(X[M x K] @ W[K x N] + bias), row-major.
// Templated tile. BM=64 always; TN==8 uses split-N fragments (2-way LDS, free).
// ---------------------------------------------------------------------------
template<int BM, int BN, int TM, int TN>
__global__ __launch_bounds__(256) void gemm_bias_act(
    const float* __restrict__ X, const float* __restrict__ W,
    const float* __restrict__ bias, float* __restrict__ Y,
    int K, int N, int act)
{
  constexpr int BK = 16;
  __shared__ float Xs[BK][BM+4];
  __shared__ float Ws[BK][BN+4];
  constexpr int NT = BN / TN;          // threads along N
  int tid = threadIdx.x;
  int tx = tid % NT, ty = tid / NT;
  long row0 = (long)blockIdx.y * BM;
  int col0 = blockIdx.x * BN;

  float acc[TM][TN];
  #pragma unroll
  for (int r = 0; r < TM; ++r)
    #pragma unroll
    for (int c = 0; c < TN; ++c) acc[r][c] = 0.f;

  constexpr int XL = (BM*BK)/(4*256);  // float4 X-loads per thread (=1)
  constexpr int WL = (BN*BK)/(4*256);  // float4 W-loads per thread (1 or 2)

  for (int kt = 0; kt < K; kt += BK){
    #pragma unroll
    for (int i = 0; i < XL; ++i){
      int f = tid + i*256;
      int m = f >> 2, k4 = (f & 3) << 2;
      float4 v = *(const float4*)&X[(row0 + m)*K + kt + k4];
      Xs[k4+0][m]=v.x; Xs[k4+1][m]=v.y; Xs[k4+2][m]=v.z; Xs[k4+3][m]=v.w;
    }
    #pragma unroll
    for (int i = 0; i < WL; ++i){
      int f = tid + i*256;
      int wk = f / (BN/4), wn = (f % (BN/4)) << 2;
      *(float4*)&Ws[wk][wn] = *(const float4*)&W[(long)(kt + wk)*N + col0 + wn];
    }
    __syncthreads();
    #pragma unroll
    for (int kk = 0; kk < BK; ++kk){
      float a[TM], bv[TN];
      *(float4*)&a[0] = *(const float4*)&Xs[kk][ty*TM];
      *(float4*)&bv[0] = *(const float4*)&Ws[kk][tx*4];
      if constexpr (TN == 8)
        *(float4*)&bv[4] = *(const float4*)&Ws[kk][BN/2 + tx*4];
      #pragma unroll
      for (int r = 0; r < TM; ++r)
        #pragma unroll
        for (int c = 0; c < TN; ++c) acc[r][c] = fmaf(a[r], bv[c], acc[r][c]);
    }
    __syncthreads();
  }

  #pragma unroll
  for (int r = 0; r < TM; ++r){
    long m = row0 + ty*TM + r;
    {
      int n = col0 + tx*4;
      float4 bb = *(const float4*)&bias[n];
      float4 o;
      o.x = acc[r][0]+bb.x; o.y = acc[r][1]+bb.y; o.z = acc[r][2]+bb.z; o.w = acc[r][3]+bb.w;
      if (act){ o.x=LKY(o.x); o.y=LKY(o.y); o.z=LKY(o.z); o.w=LKY(o.w); }
      *(float4*)&Y[m*N + n] = o;
    }
    if constexpr (TN == 8){
      int n = col0 + BN/2 + tx*4;
      float4 bb = *(const float4*)&bias[n];
      float4 o;
      o.x = acc[r][4]+bb.x; o.y = acc[r][5]+bb.y; o.z = acc[r][6]+bb.z; o.w = acc[r][7]+bb.w;
      if (act){ o.x=LKY(o.x); o.y=LKY(o.y); o.z=LKY(o.z); o.w=LKY(o.w); }
      *(float4*)&Y[m*N + n] = o;
    }
  }
}

// ---------------------------------------------------------------------------
extern "C" void kernel_launch(void* const* d_in, const int* in_sizes, int n_in,
                              void* d_out, int out_size, void* d_ws, size_t ws_size,
                              hipStream_t stream) {
  const float* in0    = (const float*)d_in[0];
  const float* enc_w1 = (const float*)d_in[1];
  const float* enc_b1 = (const float*)d_in[2];
  const float* enc_w2 = (const float*)d_in[3];
  const float* enc_b2 = (const float*)d_in[4];
  const float* enc_w3 = (const float*)d_in[5];
  const float* enc_b3 = (const float*)d_in[6];
  const float* A_w    = (const float*)d_in[7];
  const float* B_w    = (const float*)d_in[8];
  const float* dec_w1 = (const float*)d_in[9];
  const float* dec_b1 = (const float*)d_in[10];
  const float* dec_w2 = (const float*)d_in[11];
  const float* dec_b2 = (const float*)d_in[12];
  const float* dec_w3 = (const float*)d_in[13];
  const float* dec_b3 = (const float*)d_in[14];
  float* out = (float*)d_out;

  // workspace layout (floats). h1 ALIASES wend+inits (dead after pass3).
  // total = 8,585,216 floats = 34.4 MB
  float* ws    = (float*)d_ws;
  float* h1enc = ws;                  // 64*512
  float* h2enc = ws + 32768;          // 64*512
  float* P1    = ws + 65536;          // 256*256
  float* P2    = ws + 131072;         // 256*256
  float* wend  = ws + 196608;         // 128*64*256 = 2,097,152
  float* inits = ws + 2293760;        // 128*64*256 (inits[0] = z0)
  float* h1    = ws + 196608;         // 8192*512 = 4,194,304 (alias)
  float* h2    = ws + 4390912;        // 8192*512

  // Encoder (only t=0 feeds the scan; rest of encoder is dead code in ref)
  enc_dense<<<64, 256, 0, stream>>>(in0, Tt*Dd, enc_w1, enc_b1, h1enc, 256, 512, 1);
  enc_dense<<<64, 256, 0, stream>>>(h1enc, 512, enc_w2, enc_b2, h2enc, 512, 512, 1);
  enc_dense<<<64, 256, 0, stream>>>(h2enc, 512, enc_w3, enc_b3, inits, 512, 256, 1);

  // A^8 by repeated squaring
  matsq<<<256, 256, 0, stream>>>(A_w, P1);   // A^2
  matsq<<<256, 256, 0, stream>>>(P1, P2);    // A^4
  matsq<<<256, 256, 0, stream>>>(P2, P1);    // A^8

  // Pass 1: local zero-init scans -> chunk end states (512 blocks)
  scan_chunk<<<dim3(NCh, Bb/RT), 256, 0, stream>>>(in0, B_w, A_w, nullptr, wend, nullptr, 0);
  // Pass 2: chunk-boundary recurrence (64 independent batch rows)
  scan_pass2<<<64, 256, 0, stream>>>(P1, wend, inits);
  // Pass 3: replay chunks with true inits; z -> d_out (reused as scratch)
  scan_chunk<<<dim3(NCh, Bb/RT), 256, 0, stream>>>(in0, B_w, A_w, inits, nullptr, out, 1);

  // Decoder: 3-layer MLP on 65536 rows, row-chunked; all grids = 512 blocks
  for (int rc = 0; rc < DEC_CHUNKS; ++rc){
    const float* zc = out + (long)rc*DEC_ROWS*Ll;
    float* oc       = out + (long)rc*DEC_ROWS*Ll;
    gemm_bias_act<64,128,4,8><<<dim3(Ee/128, DEC_ROWS/64), 256, 0, stream>>>(zc, dec_w1, dec_b1, h1, Ll, Ee, 1);
    gemm_bias_act<64,128,4,8><<<dim3(Ee/128, DEC_ROWS/64), 256, 0, stream>>>(h1, dec_w2, dec_b2, h2, Ee, Ee, 1);
    gemm_bias_act<64,64,4,4><<<dim3(Ss/64, DEC_ROWS/64), 256, 0, stream>>>(h2, dec_w3, dec_b3, oc, Ee, Ss, 0);
  }
}

// Round 3
// 1644.436 us; speedup vs baseline: 2.4235x; 1.4215x over previous
//
#include <hip/hip_runtime.h>

// Problem dims
constexpr int Bb  = 64;      // batch
constexpr int Tt  = 1024;    // time
constexpr int Dd  = 288;     // padded input feature dim
constexpr int Ss  = 256;     // STATE_DIM
constexpr int ALa = 16;      // ACT_LEN
constexpr int Ll  = 256;     // LATENT
constexpr int Ee  = 512;     // ENC
constexpr int CC  = 8;       // scan chunk length
constexpr int NCh = 128;     // number of chunks (CC*NCh == Tt)
constexpr int RT  = 16;      // batch rows per scan workgroup (2 per thread)
constexpr int NSC = 16;      // superchunks for boundary recurrence
constexpr int SC  = 8;       // boundaries per superchunk (NSC*SC == NCh)
constexpr int DEC_CHUNKS = 8;
constexpr int DEC_ROWS = (Bb*Tt)/DEC_CHUNKS;  // 8192 rows per chunk

#define LKY(v) ((v) >= 0.f ? (v) : 0.01f*(v))

using f32x4  = __attribute__((ext_vector_type(4))) float;
using short8 = __attribute__((ext_vector_type(8))) short;

__device__ __forceinline__ unsigned short f2bf(float f){
  unsigned int u = __float_as_uint(f);
  u = (u + 0x7fffu + ((u >> 16) & 1u)) >> 16;   // RNE
  return (unsigned short)u;
}
__device__ __forceinline__ float bf2f(unsigned short h){
  return __uint_as_float(((unsigned int)h) << 16);
}

// ---------------------------------------------------------------------------
// Encoder dense layer (only t=0 rows feed the scan).
// ---------------------------------------------------------------------------
__global__ __launch_bounds__(256) void enc_dense(
    const float* __restrict__ xin, int xstride,
    const float* __restrict__ W, const float* __restrict__ bias,
    float* __restrict__ out, int K, int N, int act)
{
  int b = blockIdx.x, tid = threadIdx.x;
  __shared__ float x[512];
  for (int k = tid; k < K; k += 256) x[k] = xin[(long)b*xstride + k];
  __syncthreads();
  for (int j = tid; j < N; j += 256){
    float acc = bias[j];
    #pragma unroll 4
    for (int k = 0; k < K; ++k) acc = fmaf(x[k], W[k*N + j], acc);
    out[b*N + j] = act ? LKY(acc) : acc;
  }
}

// ---------------------------------------------------------------------------
// 256x256 matrix squaring. One block per row.
// ---------------------------------------------------------------------------
__global__ __launch_bounds__(256) void matsq(
    const float* __restrict__ Msrc, float* __restrict__ Mdst)
{
  int i = blockIdx.x, j = threadIdx.x;
  __shared__ float row[256];
  row[j] = Msrc[i*256 + j];
  __syncthreads();
  float p0=0.f,p1=0.f,p2=0.f,p3=0.f;
  #pragma unroll 8
  for (int k = 0; k < 256; k += 4){
    p0 = fmaf(row[k+0], Msrc[(k+0)*256 + j], p0);
    p1 = fmaf(row[k+1], Msrc[(k+1)*256 + j], p1);
    p2 = fmaf(row[k+2], Msrc[(k+2)*256 + j], p2);
    p3 = fmaf(row[k+3], Msrc[(k+3)*256 + j], p3);
  }
  Mdst[i*256 + j] = (p0+p1)+(p2+p3);
}

// ---------------------------------------------------------------------------
// Split fp32 weight matrix into hi/lo bf16 planes in MFMA fragment order:
// out element index o = ((k>>3)*N + n)*8 + (k&7).
// ---------------------------------------------------------------------------
__global__ __launch_bounds__(256) void prep_w(
    const float* __restrict__ W, unsigned short* __restrict__ Wh,
    unsigned short* __restrict__ Wl, int N)
{
  int o = blockIdx.x*256 + threadIdx.x;
  int j = o & 7;
  int rest = o >> 3;
  int n = rest % N;
  int t8 = rest / N;          // k-group of 8
  int k = t8*8 + j;
  float v = W[k*N + n];
  unsigned short h = f2bf(v);
  Wh[o] = h;
  Wl[o] = f2bf(v - bf2f(h));
}

// ---------------------------------------------------------------------------
// Scan over one chunk of CC steps for RT=16 batch rows (2 rows per thread).
// ---------------------------------------------------------------------------
__global__ __launch_bounds__(256) void scan_chunk(
    const float* __restrict__ in0, const float* __restrict__ Bw,
    const float* __restrict__ Aw, const float* __restrict__ inits,
    float* __restrict__ wend, float* __restrict__ zout, int with_init)
{
  int chunk = blockIdx.x, b0 = blockIdx.y * RT;
  int tid = threadIdx.x;
  int tx = tid & 31, ty = tid >> 5;
  int r0 = ty, r1 = ty + 8;
  int c0 = tx * 8;
  __shared__ float sT[Ll][RT+1];
  __shared__ float ubuf[RT][ALa];

  float4 s0a, s0b, s1a, s1b;
  if (with_init){
    const float* ip0 = &inits[((chunk*Bb) + b0 + r0)*Ll + c0];
    const float* ip1 = &inits[((chunk*Bb) + b0 + r1)*Ll + c0];
    s0a = *(const float4*)ip0; s0b = *(const float4*)(ip0+4);
    s1a = *(const float4*)ip1; s1b = *(const float4*)(ip1+4);
  } else {
    s0a = make_float4(0,0,0,0); s0b = s0a; s1a = s0a; s1b = s0a;
  }
  sT[c0+0][r0]=s0a.x; sT[c0+1][r0]=s0a.y; sT[c0+2][r0]=s0a.z; sT[c0+3][r0]=s0a.w;
  sT[c0+4][r0]=s0b.x; sT[c0+5][r0]=s0b.y; sT[c0+6][r0]=s0b.z; sT[c0+7][r0]=s0b.w;
  sT[c0+0][r1]=s1a.x; sT[c0+1][r1]=s1a.y; sT[c0+2][r1]=s1a.z; sT[c0+3][r1]=s1a.w;
  sT[c0+4][r1]=s1b.x; sT[c0+5][r1]=s1b.y; sT[c0+6][r1]=s1b.z; sT[c0+7][r1]=s1b.w;

  const float4* A4 = (const float4*)Aw;
  const float4* B4 = (const float4*)Bw;

  int ub = tid >> 4, uk = tid & 15;
  const float* uptr = in0 + (long)(b0 + ub)*(Tt*Dd) + (Ss + ALa) + uk;
  float uv = uptr[(long)(chunk*CC)*Dd];

  for (int tt = 0; tt < CC; ++tt){
    int t = chunk*CC + tt;
    ubuf[ub][uk] = uv;
    __syncthreads();
    if (tt + 1 < CC) uv = uptr[(long)(t+1)*Dd];

    float4 c0a = make_float4(0,0,0,0), c0b = c0a, c1a = c0a, c1b = c0a;
    #pragma unroll
    for (int k = 0; k < ALa; ++k){
      float u0 = ubuf[r0][k], u1 = ubuf[r1][k];
      float4 w0 = B4[k*64 + (tx<<1)];
      float4 w1 = B4[k*64 + (tx<<1) + 1];
      c0a.x=fmaf(u0,w0.x,c0a.x); c0a.y=fmaf(u0,w0.y,c0a.y); c0a.z=fmaf(u0,w0.z,c0a.z); c0a.w=fmaf(u0,w0.w,c0a.w);
      c0b.x=fmaf(u0,w1.x,c0b.x); c0b.y=fmaf(u0,w1.y,c0b.y); c0b.z=fmaf(u0,w1.z,c0b.z); c0b.w=fmaf(u0,w1.w,c0b.w);
      c1a.x=fmaf(u1,w0.x,c1a.x); c1a.y=fmaf(u1,w0.y,c1a.y); c1a.z=fmaf(u1,w0.z,c1a.z); c1a.w=fmaf(u1,w0.w,c1a.w);
      c1b.x=fmaf(u1,w1.x,c1b.x); c1b.y=fmaf(u1,w1.y,c1b.y); c1b.z=fmaf(u1,w1.z,c1b.z); c1b.w=fmaf(u1,w1.w,c1b.w);
    }
    #pragma unroll 4
    for (int k = 0; k < Ll; ++k){
      float v0 = sT[k][r0], v1 = sT[k][r1];
      float4 a0 = A4[k*64 + (tx<<1)];
      float4 a1 = A4[k*64 + (tx<<1) + 1];
      c0a.x=fmaf(v0,a0.x,c0a.x); c0a.y=fmaf(v0,a0.y,c0a.y); c0a.z=fmaf(v0,a0.z,c0a.z); c0a.w=fmaf(v0,a0.w,c0a.w);
      c0b.x=fmaf(v0,a1.x,c0b.x); c0b.y=fmaf(v0,a1.y,c0b.y); c0b.z=fmaf(v0,a1.z,c0b.z); c0b.w=fmaf(v0,a1.w,c0b.w);
      c1a.x=fmaf(v1,a0.x,c1a.x); c1a.y=fmaf(v1,a0.y,c1a.y); c1a.z=fmaf(v1,a0.z,c1a.z); c1a.w=fmaf(v1,a0.w,c1a.w);
      c1b.x=fmaf(v1,a1.x,c1b.x); c1b.y=fmaf(v1,a1.y,c1b.y); c1b.z=fmaf(v1,a1.z,c1b.z); c1b.w=fmaf(v1,a1.w,c1b.w);
    }
    __syncthreads();
    s0a=c0a; s0b=c0b; s1a=c1a; s1b=c1b;
    sT[c0+0][r0]=s0a.x; sT[c0+1][r0]=s0a.y; sT[c0+2][r0]=s0a.z; sT[c0+3][r0]=s0a.w;
    sT[c0+4][r0]=s0b.x; sT[c0+5][r0]=s0b.y; sT[c0+6][r0]=s0b.z; sT[c0+7][r0]=s0b.w;
    sT[c0+0][r1]=s1a.x; sT[c0+1][r1]=s1a.y; sT[c0+2][r1]=s1a.z; sT[c0+3][r1]=s1a.w;
    sT[c0+4][r1]=s1b.x; sT[c0+5][r1]=s1b.y; sT[c0+6][r1]=s1b.z; sT[c0+7][r1]=s1b.w;
    if (with_init){
      float4* zp0 = (float4*)&zout[((long)(b0+r0)*Tt + t)*Ll + c0];
      float4* zp1 = (float4*)&zout[((long)(b0+r1)*Tt + t)*Ll + c0];
      zp0[0] = s0a; zp0[1] = s0b;
      zp1[0] = s1a; zp1[1] = s1b;
    }
  }
  if (!with_init){
    float* w0 = &wend[((chunk*Bb) + b0 + r0)*Ll + c0];
    float* w1 = &wend[((chunk*Bb) + b0 + r1)*Ll + c0];
    *(float4*)w0 = s0a; *(float4*)(w0+4) = s0b;
    *(float4*)w1 = s1a; *(float4*)(w1+4) = s1b;
  }
}

// ---------------------------------------------------------------------------
// pass2a: zero-init local boundary scans within each superchunk.
// grid (NSC, 16): block = (superchunk s, row-group of 4). 256 thr = 4 rows x 64 colgroups.
// l_1 = wend[8s]; l_{i+1} = l_i @ A8 + wend[8s+i], i=1..7; lend[s] = l_8.
// ---------------------------------------------------------------------------
__global__ __launch_bounds__(256) void pass2_local(
    const float* __restrict__ A8, const float* __restrict__ wend,
    float* __restrict__ lend)
{
  int s = blockIdx.x, rg = blockIdx.y;
  int r = threadIdx.x >> 6, cg = threadIdx.x & 63;
  int b = rg*4 + r;
  __shared__ float cur[4][260];
  float4 l = *(const float4*)&wend[(((SC*s)*Bb) + b)*256 + cg*4];
  *(float4*)&cur[r][cg*4] = l;
  __syncthreads();
  for (int i = 1; i < SC; ++i){
    float4 acc = *(const float4*)&wend[(((SC*s+i)*Bb) + b)*256 + cg*4];
    #pragma unroll 4
    for (int k = 0; k < 256; ++k){
      float lv = cur[r][k];
      float4 a = *(const float4*)&A8[k*256 + cg*4];
      acc.x = fmaf(lv, a.x, acc.x); acc.y = fmaf(lv, a.y, acc.y);
      acc.z = fmaf(lv, a.z, acc.z); acc.w = fmaf(lv, a.w, acc.w);
    }
    __syncthreads();
    *(float4*)&cur[r][cg*4] = acc;
    l = acc;
    __syncthreads();
  }
  *(float4*)&lend[((s*Bb) + b)*256 + cg*4] = l;
}

// ---------------------------------------------------------------------------
// pass2b: superboundary recurrence g[s+1] = g[s] @ A64 + lend[s].
// g[s] written to inits[8s]. One block per batch row.
// ---------------------------------------------------------------------------
__global__ __launch_bounds__(256) void pass2_global(
    const float* __restrict__ A64, const float* __restrict__ lend,
    float* __restrict__ inits)
{
  int b = blockIdx.x, tid = threadIdx.x;
  __shared__ float cur[256];
  cur[tid] = inits[b*256 + tid];     // g[0] = z0
  __syncthreads();
  for (int s = 0; s < NSC-1; ++s){
    float p[8] = {0,0,0,0,0,0,0,0};
    #pragma unroll 4
    for (int k = 0; k < 256; k += 8){
      #pragma unroll
      for (int q = 0; q < 8; ++q)
        p[q] = fmaf(cur[k+q], A64[(k+q)*256 + tid], p[q]);
    }
    float acc = lend[((s*Bb) + b)*256 + tid]
              + (((p[0]+p[1])+(p[2]+p[3])) + ((p[4]+p[5])+(p[6]+p[7])));
    __syncthreads();
    cur[tid] = acc;
    inits[((long)((s+1)*SC)*Bb + b)*256 + tid] = acc;
    __syncthreads();
  }
}

// ---------------------------------------------------------------------------
// pass2c: replay within superchunk with true init:
// inits[8s+i+1] = inits[8s+i] @ A8 + wend[8s+i], i=0..6.
// ---------------------------------------------------------------------------
__global__ __launch_bounds__(256) void pass2_replay(
    const float* __restrict__ A8, const float* __restrict__ wend,
    float* __restrict__ inits)
{
  int s = blockIdx.x, rg = blockIdx.y;
  int r = threadIdx.x >> 6, cg = threadIdx.x & 63;
  int b = rg*4 + r;
  __shared__ float cur[4][260];
  float4 g = *(const float4*)&inits[(((SC*s)*Bb) + b)*256 + cg*4];
  *(float4*)&cur[r][cg*4] = g;
  __syncthreads();
  for (int i = 0; i < SC-1; ++i){
    float4 acc = *(const float4*)&wend[(((SC*s+i)*Bb) + b)*256 + cg*4];
    #pragma unroll 4
    for (int k = 0; k < 256; ++k){
      float lv = cur[r][k];
      float4 a = *(const float4*)&A8[k*256 + cg*4];
      acc.x = fmaf(lv, a.x, acc.x); acc.y = fmaf(lv, a.y, acc.y);
      acc.z = fmaf(lv, a.z, acc.z); acc.w = fmaf(lv, a.w, acc.w);
    }
    __syncthreads();
    *(float4*)&cur[r][cg*4] = acc;
    *(float4*)&inits[(((SC*s+i+1)*Bb) + b)*256 + cg*4] = acc;
    __syncthreads();
  }
}

// ---------------------------------------------------------------------------
// Split-bf16 MFMA GEMM: Y = act(X @ W + bias); X split into hi/lo bf16,
// W pre-split (prep_w). D = Xh*Wh + Xh*Wl + Xl*Wh (lo*lo dropped).
// 16x16x32 bf16 MFMA. Layouts (m89/m120-verified):
//   A[m=lane&15][k=quad*8+j], B[k=quad*8+j][n=lane&15],
//   C/D row=quad*4+reg, col=lane&15.
// Block: 256 thr = 4 waves (2x2). BM x BN tile, BK=32.
// INS: X from pre-split planes (SPL layout). OUTS: write hi/lo planes.
// SPL layout over (Mrows x C): elem (m,c) at ((c>>3)*Mrows + m)*8 + (c&7).
// ---------------------------------------------------------------------------
template<int BM, int BN, bool INS, bool OUTS>
__global__ __launch_bounds__(256) void gemm_mfma(
    const float* __restrict__ X,
    const unsigned short* __restrict__ Xhp, const unsigned short* __restrict__ Xlp,
    const unsigned short* __restrict__ Whp, const unsigned short* __restrict__ Wlp,
    const float* __restrict__ bias, float* __restrict__ Y,
    unsigned short* __restrict__ Yh, unsigned short* __restrict__ Yl,
    int Mrows, int K, int N, int act)
{
  constexpr int BMh = BM/2, BNh = BN/2;
  constexpr int MT = BM/32, NT = BN/32;
  __shared__ __align__(16) unsigned short Xh[4*BM*8], Xl[4*BM*8];
  __shared__ __align__(16) unsigned short Wh[4*BN*8], Wl[4*BN*8];

  int tid  = threadIdx.x;
  int wave = tid >> 6, lane = tid & 63;
  int wm = wave & 1, wn = wave >> 1;
  int quad = lane >> 4, l16 = lane & 15;
  long row0 = (long)blockIdx.y * BM;
  int col0 = blockIdx.x * BN;

  f32x4 acc[MT][NT];
  #pragma unroll
  for (int mt = 0; mt < MT; ++mt)
    #pragma unroll
    for (int nt = 0; nt < NT; ++nt) acc[mt][nt] = (f32x4){0.f,0.f,0.f,0.f};

  for (int kt = 0; kt < K; kt += 32){
    int ktile = kt >> 5;
    // ---- stage X ----
    if constexpr (INS){
      #pragma unroll
      for (int it = 0; it < (BM*4)/256; ++it){
        int idx = tid + it*256;
        int q = idx / BM, m = idx % BM;
        long src = (long)(ktile*4 + q)*Mrows + row0 + m;
        ((uint4*)Xh)[q*BM + m] = ((const uint4*)Xhp)[src];
        ((uint4*)Xl)[q*BM + m] = ((const uint4*)Xlp)[src];
      }
    } else {
      #pragma unroll
      for (int it = 0; it < (BM*4)/256; ++it){
        int idx = tid + it*256;
        int q = idx / BM, m = idx % BM;
        const float* xp = &X[(row0 + m)*(long)K + kt + q*8];
        float4 v0 = *(const float4*)xp;
        float4 v1 = *(const float4*)(xp + 4);
        float vv[8] = {v0.x,v0.y,v0.z,v0.w,v1.x,v1.y,v1.z,v1.w};
        unsigned short hs[8], ls[8];
        #pragma unroll
        for (int j = 0; j < 8; ++j){
          hs[j] = f2bf(vv[j]);
          ls[j] = f2bf(vv[j] - bf2f(hs[j]));
        }
        *(uint4*)&Xh[(q*BM + m)*8] = *(const uint4*)hs;
        *(uint4*)&Xl[(q*BM + m)*8] = *(const uint4*)ls;
      }
    }
    // ---- stage W (pre-split, fragment-ordered) ----
    #pragma unroll
    for (int it = 0; it < (BN*4)/256; ++it){
      int idx = tid + it*256;
      int q = idx / BN, n = idx % BN;
      long src = (long)(ktile*4 + q)*N + col0 + n;
      ((uint4*)Wh)[q*BN + n] = ((const uint4*)Whp)[src];
      ((uint4*)Wl)[q*BN + n] = ((const uint4*)Wlp)[src];
    }
    __syncthreads();

    short8 ah[MT], al[MT], bh[NT], bl[NT];
    #pragma unroll
    for (int mt = 0; mt < MT; ++mt){
      int off = (quad*BM + wm*BMh + mt*16 + l16)*8;
      ah[mt] = *(const short8*)&Xh[off];
      al[mt] = *(const short8*)&Xl[off];
    }
    #pragma unroll
    for (int nt = 0; nt < NT; ++nt){
      int off = (quad*BN + wn*BNh + nt*16 + l16)*8;
      bh[nt] = *(const short8*)&Wh[off];
      bl[nt] = *(const short8*)&Wl[off];
    }
    #pragma unroll
    for (int mt = 0; mt < MT; ++mt)
      #pragma unroll
      for (int nt = 0; nt < NT; ++nt){
        acc[mt][nt] = __builtin_amdgcn_mfma_f32_16x16x32_bf16(ah[mt], bh[nt], acc[mt][nt], 0, 0, 0);
        acc[mt][nt] = __builtin_amdgcn_mfma_f32_16x16x32_bf16(ah[mt], bl[nt], acc[mt][nt], 0, 0, 0);
        acc[mt][nt] = __builtin_amdgcn_mfma_f32_16x16x32_bf16(al[mt], bh[nt], acc[mt][nt], 0, 0, 0);
      }
    __syncthreads();
  }

  // ---- epilogue ----
  #pragma unroll
  for (int mt = 0; mt < MT; ++mt){
    long rowb = row0 + wm*BMh + mt*16 + quad*4;
    #pragma unroll
    for (int nt = 0; nt < NT; ++nt){
      int col = col0 + wn*BNh + nt*16 + l16;
      float bs = bias[col];
      #pragma unroll
      for (int reg = 0; reg < 4; ++reg){
        float y = acc[mt][nt][reg] + bs;
        if (act) y = LKY(y);
        long row = rowb + reg;
        if constexpr (OUTS){
          unsigned short h = f2bf(y);
          unsigned short l = f2bf(y - bf2f(h));
          long off = ((long)(col >> 3)*Mrows + row)*8 + (col & 7);
          Yh[off] = h; Yl[off] = l;
        } else {
          Y[row*(long)N + col] = y;
        }
      }
    }
  }
}

// ---------------------------------------------------------------------------
extern "C" void kernel_launch(void* const* d_in, const int* in_sizes, int n_in,
                              void* d_out, int out_size, void* d_ws, size_t ws_size,
                              hipStream_t stream) {
  const float* in0    = (const float*)d_in[0];
  const float* enc_w1 = (const float*)d_in[1];
  const float* enc_b1 = (const float*)d_in[2];
  const float* enc_w2 = (const float*)d_in[3];
  const float* enc_b2 = (const float*)d_in[4];
  const float* enc_w3 = (const float*)d_in[5];
  const float* enc_b3 = (const float*)d_in[6];
  const float* A_w    = (const float*)d_in[7];
  const float* B_w    = (const float*)d_in[8];
  const float* dec_w1 = (const float*)d_in[9];
  const float* dec_b1 = (const float*)d_in[10];
  const float* dec_w2 = (const float*)d_in[11];
  const float* dec_b2 = (const float*)d_in[12];
  const float* dec_w3 = (const float*)d_in[13];
  const float* dec_b3 = (const float*)d_in[14];
  float* out = (float*)d_out;

  // workspace layout (float slots), total 9,175,040 floats = 36.7 MB.
  // h1h/h1l alias wend/inits; h2h/h2l alias lend+tail (all dead post-scan).
  float* ws    = (float*)d_ws;
  float* h1enc = ws;                      // 32768
  float* h2enc = ws + 32768;              // 32768
  float* P1    = ws + 65536;              // 65536  (A8 final)
  float* P2    = ws + 131072;             // 65536  (scratch)
  float* P3    = ws + 196608;             // 65536  (A64 final)
  float* wend  = ws + 262144;             // 2097152
  float* inits = ws + 2359296;            // 2097152 (inits[0] = z0)
  float* lend  = ws + 4456448;            // 262144
  unsigned short* h1h = (unsigned short*)(ws + 262144);   // alias wend
  unsigned short* h1l = (unsigned short*)(ws + 2359296);  // alias inits
  unsigned short* h2h = (unsigned short*)(ws + 4456448);  // alias lend+
  unsigned short* h2l = (unsigned short*)(ws + 6553600);
  unsigned short* Whp = (unsigned short*)(ws + 8650752);  // 524288 ushorts
  unsigned short* Wlp = (unsigned short*)(ws + 8912896);  // 524288 ushorts

  // Encoder (only t=0 feeds the scan)
  enc_dense<<<64, 256, 0, stream>>>(in0, Tt*Dd, enc_w1, enc_b1, h1enc, 256, 512, 1);
  enc_dense<<<64, 256, 0, stream>>>(h1enc, 512, enc_w2, enc_b2, h2enc, 512, 512, 1);
  enc_dense<<<64, 256, 0, stream>>>(h2enc, 512, enc_w3, enc_b3, inits, 512, 256, 1);

  // A^8 (P1) and A^64 (P3) by repeated squaring
  matsq<<<256, 256, 0, stream>>>(A_w, P1);   // A2
  matsq<<<256, 256, 0, stream>>>(P1, P2);    // A4
  matsq<<<256, 256, 0, stream>>>(P2, P1);    // A8   -> P1 (keep)
  matsq<<<256, 256, 0, stream>>>(P1, P3);    // A16
  matsq<<<256, 256, 0, stream>>>(P3, P2);    // A32
  matsq<<<256, 256, 0, stream>>>(P2, P3);    // A64  -> P3 (keep)

  // Pre-split decoder weights into MFMA fragment-ordered hi/lo planes
  prep_w<<<512,  256, 0, stream>>>(dec_w1, Whp,          Wlp,          512);
  prep_w<<<1024, 256, 0, stream>>>(dec_w2, Whp + 131072, Wlp + 131072, 512);
  prep_w<<<512,  256, 0, stream>>>(dec_w3, Whp + 393216, Wlp + 393216, 256);

  // Pass 1: local zero-init scans -> chunk end states (512 blocks)
  scan_chunk<<<dim3(NCh, Bb/RT), 256, 0, stream>>>(in0, B_w, A_w, nullptr, wend, nullptr, 0);
  // Pass 2 (hierarchical boundary recurrence, depth 7+15+7)
  pass2_local <<<dim3(NSC, 16), 256, 0, stream>>>(P1, wend, lend);
  pass2_global<<<64,            256, 0, stream>>>(P3, lend, inits);
  pass2_replay<<<dim3(NSC, 16), 256, 0, stream>>>(P1, wend, inits);
  // Pass 3: replay chunks with true inits; z -> d_out (reused as scratch)
  scan_chunk<<<dim3(NCh, Bb/RT), 256, 0, stream>>>(in0, B_w, A_w, inits, nullptr, out, 1);

  // Decoder: 3-layer MLP, split-bf16 MFMA, row-chunked
  for (int rc = 0; rc < DEC_CHUNKS; ++rc){
    const float* zc = out + (long)rc*DEC_ROWS*Ll;
    float* oc       = out + (long)rc*DEC_ROWS*Ll;
    gemm_mfma<128,64,false,true><<<dim3(Ee/64, DEC_ROWS/128), 256, 0, stream>>>(
        zc, nullptr, nullptr, Whp, Wlp, dec_b1, nullptr, h1h, h1l, DEC_ROWS, Ll, Ee, 1);
    gemm_mfma<128,64,true,true><<<dim3(Ee/64, DEC_ROWS/128), 256, 0, stream>>>(
        nullptr, h1h, h1l, Whp + 131072, Wlp + 131072, dec_b2, nullptr, h2h, h2l, DEC_ROWS, Ee, Ee, 1);
    gemm_mfma<128,64,true,false><<<dim3(Ss/64, DEC_ROWS/128), 256, 0, stream>>>(
        nullptr, h2h, h2l, Whp + 393216, Wlp + 393216, dec_b3, oc, nullptr, nullptr, DEC_ROWS, Ee, Ss, 0);
  }
}

// Round 4
// 1247.205 us; speedup vs baseline: 3.1954x; 1.3185x over previous
//
#include <hip/hip_runtime.h>

// Problem dims
constexpr int Bb  = 64;      // batch
constexpr int Tt  = 1024;    // time
constexpr int Dd  = 288;     // padded input feature dim
constexpr int Ss  = 256;     // STATE_DIM
constexpr int ALa = 16;      // ACT_LEN
constexpr int Ll  = 256;     // LATENT
constexpr int Ee  = 512;     // ENC
constexpr int CC  = 8;       // scan chunk length
constexpr int NCh = 128;     // number of chunks (CC*NCh == Tt)
constexpr int NSC = 16;      // superchunks for boundary recurrence
constexpr int SC  = 8;       // chunk-boundaries per superchunk
constexpr int DEC_CHUNKS = 8;
constexpr int DEC_ROWS = (Bb*Tt)/DEC_CHUNKS;  // 8192 rows per chunk

#define LKY(v) ((v) >= 0.f ? (v) : 0.01f*(v))

using f32x4  = __attribute__((ext_vector_type(4))) float;
using short8 = __attribute__((ext_vector_type(8))) short;
typedef unsigned short ushort_t;

__device__ __forceinline__ unsigned short f2bf(float f){
  unsigned int u = __float_as_uint(f);
  u = (u + 0x7fffu + ((u >> 16) & 1u)) >> 16;   // RNE
  return (unsigned short)u;
}
__device__ __forceinline__ float bf2f(unsigned short h){
  return __uint_as_float(((unsigned int)h) << 16);
}

// ---------------------------------------------------------------------------
// Encoder dense layer (only t=0 rows feed the scan).
// ---------------------------------------------------------------------------
__global__ __launch_bounds__(256) void enc_dense(
    const float* __restrict__ xin, int xstride,
    const float* __restrict__ W, const float* __restrict__ bias,
    float* __restrict__ out, int K, int N, int act)
{
  int b = blockIdx.x, tid = threadIdx.x;
  __shared__ float x[512];
  for (int k = tid; k < K; k += 256) x[k] = xin[(long)b*xstride + k];
  __syncthreads();
  for (int j = tid; j < N; j += 256){
    float acc = bias[j];
    #pragma unroll 4
    for (int k = 0; k < K; ++k) acc = fmaf(x[k], W[k*N + j], acc);
    out[b*N + j] = act ? LKY(acc) : acc;
  }
}

// ---------------------------------------------------------------------------
// General 256x256 matmul C = X @ Y, optional fp32 out, optional split planes.
// Plane format (k,n): ((k>>3)*256 + n)*8 + (k&7).
// ---------------------------------------------------------------------------
__global__ __launch_bounds__(256) void matmul_g(
    const float* __restrict__ X, const float* __restrict__ Y,
    float* __restrict__ Cf, ushort_t* __restrict__ Ch, ushort_t* __restrict__ Cl)
{
  int i = blockIdx.x, j = threadIdx.x;
  __shared__ float row[256];
  row[j] = X[i*256 + j];
  __syncthreads();
  float p0=0.f,p1=0.f,p2=0.f,p3=0.f;
  #pragma unroll 8
  for (int k = 0; k < 256; k += 4){
    p0 = fmaf(row[k+0], Y[(k+0)*256 + j], p0);
    p1 = fmaf(row[k+1], Y[(k+1)*256 + j], p1);
    p2 = fmaf(row[k+2], Y[(k+2)*256 + j], p2);
    p3 = fmaf(row[k+3], Y[(k+3)*256 + j], p3);
  }
  float c = (p0+p1)+(p2+p3);
  if (Cf) Cf[i*256 + j] = c;
  if (Ch){
    ushort_t h = f2bf(c);
    int o = ((i>>3)*256 + j)*8 + (i&7);
    Ch[o] = h; Cl[o] = f2bf(c - bf2f(h));
  }
}

// ---------------------------------------------------------------------------
// Split fp32 weight matrix (KxN) into hi/lo bf16 planes in fragment order.
// ---------------------------------------------------------------------------
__global__ __launch_bounds__(256) void prep_w(
    const float* __restrict__ W, ushort_t* __restrict__ Wh,
    ushort_t* __restrict__ Wl, int N)
{
  int o = blockIdx.x*256 + threadIdx.x;
  int j = o & 7;
  int rest = o >> 3;
  int n = rest % N;
  int t8 = rest / N;
  int k = t8*8 + j;
  float v = W[k*N + n];
  ushort_t h = f2bf(v);
  Wh[o] = h;
  Wl[o] = f2bf(v - bf2f(h));
}

// ---------------------------------------------------------------------------
// B_w^T plane for the scan's u-term: K padded 16->32 (zeros), N=256.
// ---------------------------------------------------------------------------
__global__ __launch_bounds__(256) void prep_bw(
    const float* __restrict__ B, ushort_t* __restrict__ Bh, ushort_t* __restrict__ Bl)
{
  int o = blockIdx.x*256 + threadIdx.x;     // 8192 total
  int j = o & 7, rest = o >> 3;
  int n = rest & 255, kq = rest >> 8;
  int k = kq*8 + j;
  float v = (k < ALa) ? B[k*256 + n] : 0.f;
  ushort_t h = f2bf(v);
  Bh[o] = h; Bl[o] = f2bf(v - bf2f(h));
}

// ---------------------------------------------------------------------------
// MFMA chunk scan (zero-init pass only). Transposed state St = z^T:
// St_new = A^T*St + B^T*u^T, so MFMA A-operand = A^T (streamed from pre-split
// planes) and C/D columns = batch. One block per chunk; 4 waves, each wave owns
// 64 latent-out rows x all 64 batch cols. Writes w[t] to zout and chunk-end
// to wend. Split-bf16, 3 products.
// ---------------------------------------------------------------------------
__device__ __forceinline__ void load_afrag(
    const ushort_t* __restrict__ P, int kq, int m0, short8* dst)
{
  #pragma unroll
  for (int mt = 0; mt < 4; ++mt)
    dst[mt] = *(const short8*)&P[((long)kq*256 + m0 + mt*16)*8];
}

__global__ __launch_bounds__(256) void scan_mfma(
    const float* __restrict__ in0,
    const ushort_t* __restrict__ AtH, const ushort_t* __restrict__ AtL,
    const ushort_t* __restrict__ BtH, const ushort_t* __restrict__ BtL,
    float* __restrict__ wend, float* __restrict__ zout)
{
  int chunk = blockIdx.x;
  int tid = threadIdx.x;
  int wave = tid >> 6, lane = tid & 63;
  int quad = lane >> 4, l16 = lane & 15;
  int mwave = wave * 64;                  // latent-out base rows for this wave
  int m0 = mwave + l16;

  __shared__ ushort_t StH[16384];         // ((k>>3)*64 + n)*8 + (k&7), 32 KB
  __shared__ ushort_t StL[16384];

  // constant B^T fragments (A-operand of u-term), K=32 padded
  short8 Bfh[4], Bfl[4];
  #pragma unroll
  for (int mt = 0; mt < 4; ++mt){
    int off = ((quad)*256 + m0 + mt*16)*8;
    Bfh[mt] = *(const short8*)&BtH[off];
    Bfl[mt] = *(const short8*)&BtL[off];
  }

  f32x4 acc[4][4];
  #pragma unroll
  for (int mt = 0; mt < 4; ++mt)
    #pragma unroll
    for (int nt = 0; nt < 4; ++nt) acc[mt][nt] = (f32x4){0.f,0.f,0.f,0.f};

  // per-lane u base pointers (batch row = nt*16+l16, k-offset = quad*8)
  const float* ubase[4];
  #pragma unroll
  for (int nt = 0; nt < 4; ++nt)
    ubase[nt] = in0 + (long)(nt*16 + l16)*(Tt*Dd) + (Ss + ALa) + quad*8;

  short8 Ahb[2][4], Alb[2][4];

  for (int tt = 0; tt < CC; ++tt){
    int t = chunk*CC + tt;
    // issue u loads early (consumed after the kt loop)
    float4 uq[4][2];
    #pragma unroll
    for (int nt = 0; nt < 4; ++nt){
      if (quad < 2){
        const float* up = ubase[nt] + (long)t*Dd;
        uq[nt][0] = *(const float4*)up;
        uq[nt][1] = *(const float4*)(up + 4);
      } else {
        uq[nt][0] = make_float4(0,0,0,0); uq[nt][1] = make_float4(0,0,0,0);
      }
    }

    if (tt > 0){
      load_afrag(AtH, 0*4 + quad, m0, Ahb[0]);
      load_afrag(AtL, 0*4 + quad, m0, Alb[0]);
      #pragma unroll
      for (int kt = 0; kt < 8; ++kt){
        int cur = kt & 1;
        if (kt < 7){
          load_afrag(AtH, (kt+1)*4 + quad, m0, Ahb[cur^1]);
          load_afrag(AtL, (kt+1)*4 + quad, m0, Alb[cur^1]);
        }
        short8 Sbh[4], Sbl[4];
        #pragma unroll
        for (int nt = 0; nt < 4; ++nt){
          int off = ((kt*4 + quad)*64 + nt*16 + l16)*8;
          Sbh[nt] = *(const short8*)&StH[off];
          Sbl[nt] = *(const short8*)&StL[off];
        }
        #pragma unroll
        for (int mt = 0; mt < 4; ++mt)
          #pragma unroll
          for (int nt = 0; nt < 4; ++nt){
            acc[mt][nt] = __builtin_amdgcn_mfma_f32_16x16x32_bf16(Ahb[cur][mt], Sbh[nt], acc[mt][nt], 0,0,0);
            acc[mt][nt] = __builtin_amdgcn_mfma_f32_16x16x32_bf16(Ahb[cur][mt], Sbl[nt], acc[mt][nt], 0,0,0);
            acc[mt][nt] = __builtin_amdgcn_mfma_f32_16x16x32_bf16(Alb[cur][mt], Sbh[nt], acc[mt][nt], 0,0,0);
          }
      }
    }

    // u-term: split u into hi/lo frags, 3 products
    short8 uh[4], ul[4];
    #pragma unroll
    for (int nt = 0; nt < 4; ++nt){
      float v[8] = {uq[nt][0].x,uq[nt][0].y,uq[nt][0].z,uq[nt][0].w,
                    uq[nt][1].x,uq[nt][1].y,uq[nt][1].z,uq[nt][1].w};
      ushort_t hs[8], ls[8];
      #pragma unroll
      for (int j = 0; j < 8; ++j){
        hs[j] = f2bf(v[j]);
        ls[j] = f2bf(v[j] - bf2f(hs[j]));
      }
      uh[nt] = *(const short8*)hs; ul[nt] = *(const short8*)ls;
    }
    #pragma unroll
    for (int mt = 0; mt < 4; ++mt)
      #pragma unroll
      for (int nt = 0; nt < 4; ++nt){
        acc[mt][nt] = __builtin_amdgcn_mfma_f32_16x16x32_bf16(Bfh[mt], uh[nt], acc[mt][nt], 0,0,0);
        acc[mt][nt] = __builtin_amdgcn_mfma_f32_16x16x32_bf16(Bfh[mt], ul[nt], acc[mt][nt], 0,0,0);
        acc[mt][nt] = __builtin_amdgcn_mfma_f32_16x16x32_bf16(Bfl[mt], uh[nt], acc[mt][nt], 0,0,0);
      }

    __syncthreads();   // all St reads of this step done

    // write-out: zout (+wend at last step) + new St planes; reset acc
    #pragma unroll
    for (int mt = 0; mt < 4; ++mt){
      int mb = mwave + mt*16 + quad*4;
      #pragma unroll
      for (int nt = 0; nt < 4; ++nt){
        int n = nt*16 + l16;
        f32x4 v = acc[mt][nt];
        *(float4*)&zout[((long)n*Tt + t)*Ll + mb] = make_float4(v[0],v[1],v[2],v[3]);
        if (tt == CC-1)
          *(float4*)&wend[((long)chunk*Bb + n)*Ll + mb] = make_float4(v[0],v[1],v[2],v[3]);
        #pragma unroll
        for (int reg = 0; reg < 4; ++reg){
          int m = mb + reg;
          ushort_t h = f2bf(v[reg]);
          ushort_t l = f2bf(v[reg] - bf2f(h));
          int so = ((m>>3)*64 + n)*8 + (m&7);
          StH[so] = h; StL[so] = l;
        }
        acc[mt][nt] = (f32x4){0.f,0.f,0.f,0.f};
      }
    }
    __syncthreads();   // new St visible for next step
  }
}

// ---------------------------------------------------------------------------
// pass2a: zero-init local boundary scans within each superchunk (fp32).
// ---------------------------------------------------------------------------
__global__ __launch_bounds__(256) void pass2_local(
    const float* __restrict__ A8, const float* __restrict__ wend,
    float* __restrict__ lend)
{
  int s = blockIdx.x, rg = blockIdx.y;
  int r = threadIdx.x >> 6, cg = threadIdx.x & 63;
  int b = rg*4 + r;
  __shared__ float cur[4][260];
  float4 l = *(const float4*)&wend[(((SC*s)*Bb) + b)*256 + cg*4];
  *(float4*)&cur[r][cg*4] = l;
  __syncthreads();
  for (int i = 1; i < SC; ++i){
    float4 acc = *(const float4*)&wend[(((SC*s+i)*Bb) + b)*256 + cg*4];
    #pragma unroll 4
    for (int k = 0; k < 256; ++k){
      float lv = cur[r][k];
      float4 a = *(const float4*)&A8[k*256 + cg*4];
      acc.x = fmaf(lv, a.x, acc.x); acc.y = fmaf(lv, a.y, acc.y);
      acc.z = fmaf(lv, a.z, acc.z); acc.w = fmaf(lv, a.w, acc.w);
    }
    __syncthreads();
    *(float4*)&cur[r][cg*4] = acc;
    l = acc;
    __syncthreads();
  }
  *(float4*)&lend[((s*Bb) + b)*256 + cg*4] = l;
}

// ---------------------------------------------------------------------------
// pass2b: superboundary recurrence g[s+1] = g[s] @ A64 + lend[s].
// ---------------------------------------------------------------------------
__global__ __launch_bounds__(256) void pass2_global(
    const float* __restrict__ A64, const float* __restrict__ lend,
    float* __restrict__ inits)
{
  int b = blockIdx.x, tid = threadIdx.x;
  __shared__ float cur[256];
  cur[tid] = inits[b*256 + tid];     // g[0] = z0
  __syncthreads();
  for (int s = 0; s < NSC-1; ++s){
    float p[8] = {0,0,0,0,0,0,0,0};
    #pragma unroll 4
    for (int k = 0; k < 256; k += 8){
      #pragma unroll
      for (int q = 0; q < 8; ++q)
        p[q] = fmaf(cur[k+q], A64[(k+q)*256 + tid], p[q]);
    }
    float acc = lend[((s*Bb) + b)*256 + tid]
              + (((p[0]+p[1])+(p[2]+p[3])) + ((p[4]+p[5])+(p[6]+p[7])));
    __syncthreads();
    cur[tid] = acc;
    inits[((long)((s+1)*SC)*Bb + b)*256 + tid] = acc;
    __syncthreads();
  }
}

// ---------------------------------------------------------------------------
// pass2c: replay within superchunk with true init.
// ---------------------------------------------------------------------------
__global__ __launch_bounds__(256) void pass2_replay(
    const float* __restrict__ A8, const float* __restrict__ wend,
    float* __restrict__ inits)
{
  int s = blockIdx.x, rg = blockIdx.y;
  int r = threadIdx.x >> 6, cg = threadIdx.x & 63;
  int b = rg*4 + r;
  __shared__ float cur[4][260];
  float4 g = *(const float4*)&inits[(((SC*s)*Bb) + b)*256 + cg*4];
  *(float4*)&cur[r][cg*4] = g;
  __syncthreads();
  for (int i = 0; i < SC-1; ++i){
    float4 acc = *(const float4*)&wend[(((SC*s+i)*Bb) + b)*256 + cg*4];
    #pragma unroll 4
    for (int k = 0; k < 256; ++k){
      float lv = cur[r][k];
      float4 a = *(const float4*)&A8[k*256 + cg*4];
      acc.x = fmaf(lv, a.x, acc.x); acc.y = fmaf(lv, a.y, acc.y);
      acc.z = fmaf(lv, a.z, acc.z); acc.w = fmaf(lv, a.w, acc.w);
    }
    __syncthreads();
    *(float4*)&cur[r][cg*4] = acc;
    *(float4*)&inits[(((SC*s+i+1)*Bb) + b)*256 + cg*4] = acc;
    __syncthreads();
  }
}

// ---------------------------------------------------------------------------
// Correction GEMMs: out[b, c*CC+j, :] += inits[c*64+b] @ A^(j+1).
// grid (N/128, M/128, 8); BM=BN=128, K=256, waves 2x2, split-bf16 3-product.
// ---------------------------------------------------------------------------
__global__ __launch_bounds__(256) void gemm_corr(
    const float* __restrict__ inits, const ushort_t* __restrict__ AjH,
    const ushort_t* __restrict__ AjL, float* __restrict__ out)
{
  int jz = blockIdx.z;                         // t-offset; power = jz+1
  const ushort_t* Whp = AjH + (long)jz*65536;
  const ushort_t* Wlp = AjL + (long)jz*65536;
  __shared__ __align__(16) ushort_t Xh[4*128*8], Xl[4*128*8];
  __shared__ __align__(16) ushort_t Wh[4*128*8], Wl[4*128*8];

  int tid  = threadIdx.x;
  int wave = tid >> 6, lane = tid & 63;
  int wm = wave & 1, wn = wave >> 1;
  int quad = lane >> 4, l16 = lane & 15;
  int row0 = blockIdx.y * 128;
  int col0 = blockIdx.x * 128;

  f32x4 acc[4][4];
  #pragma unroll
  for (int mt = 0; mt < 4; ++mt)
    #pragma unroll
    for (int nt = 0; nt < 4; ++nt) acc[mt][nt] = (f32x4){0.f,0.f,0.f,0.f};

  for (int kt = 0; kt < 8; ++kt){
    #pragma unroll
    for (int it = 0; it < 2; ++it){
      int idx = tid + it*256;
      int q = idx >> 7, m = idx & 127;
      const float* xp = &inits[(long)(row0 + m)*256 + kt*32 + q*8];
      float4 v0 = *(const float4*)xp;
      float4 v1 = *(const float4*)(xp + 4);
      float vv[8] = {v0.x,v0.y,v0.z,v0.w,v1.x,v1.y,v1.z,v1.w};
      ushort_t hs[8], ls[8];
      #pragma unroll
      for (int j = 0; j < 8; ++j){
        hs[j] = f2bf(vv[j]);
        ls[j] = f2bf(vv[j] - bf2f(hs[j]));
      }
      *(uint4*)&Xh[(q*128 + m)*8] = *(const uint4*)hs;
      *(uint4*)&Xl[(q*128 + m)*8] = *(const uint4*)ls;
      int n = idx & 127;
      long src = (long)(kt*4 + q)*256 + col0 + n;
      ((uint4*)Wh)[q*128 + n] = ((const uint4*)Whp)[src];
      ((uint4*)Wl)[q*128 + n] = ((const uint4*)Wlp)[src];
    }
    __syncthreads();
    short8 ah[4], al[4], bh[4], bl[4];
    #pragma unroll
    for (int mt = 0; mt < 4; ++mt){
      int off = (quad*128 + wm*64 + mt*16 + l16)*8;
      ah[mt] = *(const short8*)&Xh[off];
      al[mt] = *(const short8*)&Xl[off];
    }
    #pragma unroll
    for (int nt = 0; nt < 4; ++nt){
      int off = (quad*128 + wn*64 + nt*16 + l16)*8;
      bh[nt] = *(const short8*)&Wh[off];
      bl[nt] = *(const short8*)&Wl[off];
    }
    #pragma unroll
    for (int mt = 0; mt < 4; ++mt)
      #pragma unroll
      for (int nt = 0; nt < 4; ++nt){
        acc[mt][nt] = __builtin_amdgcn_mfma_f32_16x16x32_bf16(ah[mt], bh[nt], acc[mt][nt], 0,0,0);
        acc[mt][nt] = __builtin_amdgcn_mfma_f32_16x16x32_bf16(ah[mt], bl[nt], acc[mt][nt], 0,0,0);
        acc[mt][nt] = __builtin_amdgcn_mfma_f32_16x16x32_bf16(al[mt], bh[nt], acc[mt][nt], 0,0,0);
      }
    __syncthreads();
  }

  #pragma unroll
  for (int mt = 0; mt < 4; ++mt){
    #pragma unroll
    for (int nt = 0; nt < 4; ++nt){
      int col = col0 + wn*64 + nt*16 + l16;
      #pragma unroll
      for (int reg = 0; reg < 4; ++reg){
        int row = row0 + wm*64 + mt*16 + quad*4 + reg;
        int b = row & 63, c = row >> 6;
        int t = c*CC + jz;
        long addr = ((long)b*Tt + t)*Ll + col;
        out[addr] += acc[mt][nt][reg];
      }
    }
  }
}

// ---------------------------------------------------------------------------
// Decoder split-bf16 MFMA GEMM (unchanged from round 3 — known-good).
// ---------------------------------------------------------------------------
template<int BM, int BN, bool INS, bool OUTS>
__global__ __launch_bounds__(256) void gemm_mfma(
    const float* __restrict__ X,
    const ushort_t* __restrict__ Xhp, const ushort_t* __restrict__ Xlp,
    const ushort_t* __restrict__ Whp, const ushort_t* __restrict__ Wlp,
    const float* __restrict__ bias, float* __restrict__ Y,
    ushort_t* __restrict__ Yh, ushort_t* __restrict__ Yl,
    int Mrows, int K, int N, int act)
{
  constexpr int BMh = BM/2, BNh = BN/2;
  constexpr int MT = BM/32, NT = BN/32;
  __shared__ __align__(16) ushort_t Xh[4*BM*8], Xl[4*BM*8];
  __shared__ __align__(16) ushort_t Wh[4*BN*8], Wl[4*BN*8];

  int tid  = threadIdx.x;
  int wave = tid >> 6, lane = tid & 63;
  int wm = wave & 1, wn = wave >> 1;
  int quad = lane >> 4, l16 = lane & 15;
  long row0 = (long)blockIdx.y * BM;
  int col0 = blockIdx.x * BN;

  f32x4 acc[MT][NT];
  #pragma unroll
  for (int mt = 0; mt < MT; ++mt)
    #pragma unroll
    for (int nt = 0; nt < NT; ++nt) acc[mt][nt] = (f32x4){0.f,0.f,0.f,0.f};

  for (int kt = 0; kt < K; kt += 32){
    int ktile = kt >> 5;
    if constexpr (INS){
      #pragma unroll
      for (int it = 0; it < (BM*4)/256; ++it){
        int idx = tid + it*256;
        int q = idx / BM, m = idx % BM;
        long src = (long)(ktile*4 + q)*Mrows + row0 + m;
        ((uint4*)Xh)[q*BM + m] = ((const uint4*)Xhp)[src];
        ((uint4*)Xl)[q*BM + m] = ((const uint4*)Xlp)[src];
      }
    } else {
      #pragma unroll
      for (int it = 0; it < (BM*4)/256; ++it){
        int idx = tid + it*256;
        int q = idx / BM, m = idx % BM;
        const float* xp = &X[(row0 + m)*(long)K + kt + q*8];
        float4 v0 = *(const float4*)xp;
        float4 v1 = *(const float4*)(xp + 4);
        float vv[8] = {v0.x,v0.y,v0.z,v0.w,v1.x,v1.y,v1.z,v1.w};
        ushort_t hs[8], ls[8];
        #pragma unroll
        for (int j = 0; j < 8; ++j){
          hs[j] = f2bf(vv[j]);
          ls[j] = f2bf(vv[j] - bf2f(hs[j]));
        }
        *(uint4*)&Xh[(q*BM + m)*8] = *(const uint4*)hs;
        *(uint4*)&Xl[(q*BM + m)*8] = *(const uint4*)ls;
      }
    }
    #pragma unroll
    for (int it = 0; it < (BN*4)/256; ++it){
      int idx = tid + it*256;
      int q = idx / BN, n = idx % BN;
      long src = (long)(ktile*4 + q)*N + col0 + n;
      ((uint4*)Wh)[q*BN + n] = ((const uint4*)Whp)[src];
      ((uint4*)Wl)[q*BN + n] = ((const uint4*)Wlp)[src];
    }
    __syncthreads();

    short8 ah[MT], al[MT], bh[NT], bl[NT];
    #pragma unroll
    for (int mt = 0; mt < MT; ++mt){
      int off = (quad*BM + wm*BMh + mt*16 + l16)*8;
      ah[mt] = *(const short8*)&Xh[off];
      al[mt] = *(const short8*)&Xl[off];
    }
    #pragma unroll
    for (int nt = 0; nt < NT; ++nt){
      int off = (quad*BN + wn*BNh + nt*16 + l16)*8;
      bh[nt] = *(const short8*)&Wh[off];
      bl[nt] = *(const short8*)&Wl[off];
    }
    #pragma unroll
    for (int mt = 0; mt < MT; ++mt)
      #pragma unroll
      for (int nt = 0; nt < NT; ++nt){
        acc[mt][nt] = __builtin_amdgcn_mfma_f32_16x16x32_bf16(ah[mt], bh[nt], acc[mt][nt], 0, 0, 0);
        acc[mt][nt] = __builtin_amdgcn_mfma_f32_16x16x32_bf16(ah[mt], bl[nt], acc[mt][nt], 0, 0, 0);
        acc[mt][nt] = __builtin_amdgcn_mfma_f32_16x16x32_bf16(al[mt], bh[nt], acc[mt][nt], 0, 0, 0);
      }
    __syncthreads();
  }

  #pragma unroll
  for (int mt = 0; mt < MT; ++mt){
    long rowb = row0 + wm*BMh + mt*16 + quad*4;
    #pragma unroll
    for (int nt = 0; nt < NT; ++nt){
      int col = col0 + wn*BNh + nt*16 + l16;
      float bs = bias[col];
      #pragma unroll
      for (int reg = 0; reg < 4; ++reg){
        float y = acc[mt][nt][reg] + bs;
        if (act) y = LKY(y);
        long row = rowb + reg;
        if constexpr (OUTS){
          ushort_t h = f2bf(y);
          ushort_t l = f2bf(y - bf2f(h));
          long off = ((long)(col >> 3)*Mrows + row)*8 + (col & 7);
          Yh[off] = h; Yl[off] = l;
        } else {
          Y[row*(long)N + col] = y;
        }
      }
    }
  }
}

// ---------------------------------------------------------------------------
extern "C" void kernel_launch(void* const* d_in, const int* in_sizes, int n_in,
                              void* d_out, int out_size, void* d_ws, size_t ws_size,
                              hipStream_t stream) {
  const float* in0    = (const float*)d_in[0];
  const float* enc_w1 = (const float*)d_in[1];
  const float* enc_b1 = (const float*)d_in[2];
  const float* enc_w2 = (const float*)d_in[3];
  const float* enc_b2 = (const float*)d_in[4];
  const float* enc_w3 = (const float*)d_in[5];
  const float* enc_b3 = (const float*)d_in[6];
  const float* A_w    = (const float*)d_in[7];
  const float* B_w    = (const float*)d_in[8];
  const float* dec_w1 = (const float*)d_in[9];
  const float* dec_b1 = (const float*)d_in[10];
  const float* dec_w2 = (const float*)d_in[11];
  const float* dec_b2 = (const float*)d_in[12];
  const float* dec_w3 = (const float*)d_in[13];
  const float* dec_b3 = (const float*)d_in[14];
  float* out = (float*)d_out;

  // ---- workspace layout (float slots); total 9,437,184 fl = 37.75 MB ----
  float* ws    = (float*)d_ws;
  float* h1enc = ws;                      // 32768
  float* h2enc = ws + 32768;              // 32768
  float* s2    = ws + 65536;              // A^2
  float* s3    = ws + 131072;             // A^3
  float* s4    = ws + 196608;             // A^4
  float* s8    = ws + 262144;             // A^8 (pass2)
  float* s16   = ws + 327680;
  float* s32   = ws + 393216;
  float* s64   = ws + 458752;             // A^64 (pass2b)
  ushort_t* Whp_d = (ushort_t*)(ws + 524288);   // decoder W planes, 524288 ush
  ushort_t* Wlp_d = (ushort_t*)(ws + 786432);
  float* Rf    = ws + 1048576;            // R-pool: 8,388,608 fl
  // scan-phase layout of R:
  ushort_t* AjH = (ushort_t*)Rf;                // 8 planes x 65536 ush
  ushort_t* AjL = (ushort_t*)(Rf + 262144);
  ushort_t* BtH = (ushort_t*)(Rf + 524288);     // 8192 ush
  ushort_t* BtL = BtH + 8192;
  float* wend  = Rf + 532480;             // 2,097,152
  float* inits = Rf + 2629632;            // 2,097,152 (inits[0] = z0)
  float* lend  = Rf + 4726784;            // 262,144
  // decoder-phase aliases of R (scan data dead by then):
  ushort_t* h1h = (ushort_t*)Rf;
  ushort_t* h1l = (ushort_t*)(Rf + 2097152);
  ushort_t* h2h = (ushort_t*)(Rf + 4194304);
  ushort_t* h2l = (ushort_t*)(Rf + 6291456);

  // Encoder (only t=0 feeds the scan) -> z0 into inits[0]
  enc_dense<<<64, 256, 0, stream>>>(in0, Tt*Dd, enc_w1, enc_b1, h1enc, 256, 512, 1);
  enc_dense<<<64, 256, 0, stream>>>(h1enc, 512, enc_w2, enc_b2, h2enc, 512, 512, 1);
  enc_dense<<<64, 256, 0, stream>>>(h2enc, 512, enc_w3, enc_b3, inits, 512, 256, 1);

  // A^j planes (j=1..8) + fp32 A^8 / A^64 for pass2
  prep_w<<<256, 256, 0, stream>>>(A_w, AjH, AjL, 256);                       // A^1 plane
  prep_bw<<<32, 256, 0, stream>>>(B_w, BtH, BtL);
  matmul_g<<<256, 256, 0, stream>>>(A_w, A_w, s2, AjH+1*65536, AjL+1*65536); // A^2
  matmul_g<<<256, 256, 0, stream>>>(s2, A_w, s3, AjH+2*65536, AjL+2*65536);  // A^3
  matmul_g<<<256, 256, 0, stream>>>(s2, s2, s4, AjH+3*65536, AjL+3*65536);   // A^4
  matmul_g<<<256, 256, 0, stream>>>(s4, A_w, nullptr, AjH+4*65536, AjL+4*65536); // A^5
  matmul_g<<<256, 256, 0, stream>>>(s4, s2, nullptr, AjH+5*65536, AjL+5*65536);  // A^6
  matmul_g<<<256, 256, 0, stream>>>(s4, s3, nullptr, AjH+6*65536, AjL+6*65536);  // A^7
  matmul_g<<<256, 256, 0, stream>>>(s4, s4, s8, AjH+7*65536, AjL+7*65536);   // A^8
  matmul_g<<<256, 256, 0, stream>>>(s8, s8, s16, nullptr, nullptr);          // A^16
  matmul_g<<<256, 256, 0, stream>>>(s16, s16, s32, nullptr, nullptr);        // A^32
  matmul_g<<<256, 256, 0, stream>>>(s32, s32, s64, nullptr, nullptr);        // A^64

  // Decoder weight planes
  prep_w<<<512,  256, 0, stream>>>(dec_w1, Whp_d,          Wlp_d,          512);
  prep_w<<<1024, 256, 0, stream>>>(dec_w2, Whp_d + 131072, Wlp_d + 131072, 512);
  prep_w<<<512,  256, 0, stream>>>(dec_w3, Whp_d + 393216, Wlp_d + 393216, 256);

  // Pass 1: MFMA zero-init chunk scans; w[t] -> d_out, ends -> wend
  scan_mfma<<<NCh, 256, 0, stream>>>(in0, AjH, AjL, BtH, BtL, wend, out);
  // Pass 2: hierarchical boundary recurrence (fp32, depth 7+15+7)
  pass2_local <<<dim3(NSC, 16), 256, 0, stream>>>(s8, wend, lend);
  pass2_global<<<64,            256, 0, stream>>>(s64, lend, inits);
  pass2_replay<<<dim3(NSC, 16), 256, 0, stream>>>(s8, wend, inits);
  // Pass 3 (parallel corrections): out[b, c*8+j, :] += inits[c] @ A^(j+1)
  gemm_corr<<<dim3(2, 64, 8), 256, 0, stream>>>(inits, AjH, AjL, out);

  // Decoder: 3-layer MLP, split-bf16 MFMA, row-chunked
  for (int rc = 0; rc < DEC_CHUNKS; ++rc){
    const float* zc = out + (long)rc*DEC_ROWS*Ll;
    float* oc       = out + (long)rc*DEC_ROWS*Ll;
    gemm_mfma<128,64,false,true><<<dim3(Ee/64, DEC_ROWS/128), 256, 0, stream>>>(
        zc, nullptr, nullptr, Whp_d, Wlp_d, dec_b1, nullptr, h1h, h1l, DEC_ROWS, Ll, Ee, 1);
    gemm_mfma<128,64,true,true><<<dim3(Ee/64, DEC_ROWS/128), 256, 0, stream>>>(
        nullptr, h1h, h1l, Whp_d + 131072, Wlp_d + 131072, dec_b2, nullptr, h2h, h2l, DEC_ROWS, Ee, Ee, 1);
    gemm_mfma<128,64,true,false><<<dim3(Ss/64, DEC_ROWS/128), 256, 0, stream>>>(
        nullptr, h2h, h2l, Whp_d + 393216, Wlp_d + 393216, dec_b3, oc, nullptr, nullptr, DEC_ROWS, Ee, Ss, 0);
  }
}

// Round 5
// 1009.051 us; speedup vs baseline: 3.9496x; 1.2360x over previous
//
#include <hip/hip_runtime.h>

// Problem dims
constexpr int Bb  = 64;      // batch
constexpr int Tt  = 1024;    // time
constexpr int Dd  = 288;     // padded input feature dim
constexpr int Ss  = 256;     // STATE_DIM
constexpr int ALa = 16;      // ACT_LEN
constexpr int Ll  = 256;     // LATENT
constexpr int Ee  = 512;     // ENC
constexpr int CC  = 8;       // scan chunk length
constexpr int NCh = 128;     // number of chunks (CC*NCh == Tt)
constexpr int NSC = 16;      // superchunks for boundary recurrence
constexpr int SC  = 8;       // chunk-boundaries per superchunk
constexpr int DEC_CHUNKS = 8;
constexpr int DEC_ROWS = (Bb*Tt)/DEC_CHUNKS;  // 8192 rows per chunk

#define LKY(v) ((v) >= 0.f ? (v) : 0.01f*(v))

using f32x4  = __attribute__((ext_vector_type(4))) float;
using short8 = __attribute__((ext_vector_type(8))) short;
typedef unsigned short ushort_t;

__device__ __forceinline__ unsigned short f2bf(float f){
  unsigned int u = __float_as_uint(f);
  u = (u + 0x7fffu + ((u >> 16) & 1u)) >> 16;   // RNE
  return (unsigned short)u;
}
__device__ __forceinline__ float bf2f(unsigned short h){
  return __uint_as_float(((unsigned int)h) << 16);
}

// ---------------------------------------------------------------------------
// Encoder dense layer, split-K: grid (row, N/32); 256 thr = 32 cols x 8 kslc.
// ---------------------------------------------------------------------------
__global__ __launch_bounds__(256) void enc_dense(
    const float* __restrict__ xin, int xstride,
    const float* __restrict__ W, const float* __restrict__ bias,
    float* __restrict__ out, int K, int N, int act)
{
  int b = blockIdx.x, col0 = blockIdx.y * 32;
  int tid = threadIdx.x;
  int tx = tid & 31, tk = tid >> 5;
  __shared__ float x[512];
  __shared__ float part[8][33];
  for (int k = tid; k < K; k += 256) x[k] = xin[(long)b*xstride + k];
  __syncthreads();
  int j = col0 + tx;
  float p0=0.f,p1=0.f,p2=0.f,p3=0.f;
  int iters = K >> 3;
  #pragma unroll 2
  for (int i = 0; i < iters; i += 4){
    int k0 = tk + 8*i;
    p0 = fmaf(x[k0     ], W[(long)(k0     )*N + j], p0);
    p1 = fmaf(x[k0 +  8], W[(long)(k0 +  8)*N + j], p1);
    p2 = fmaf(x[k0 + 16], W[(long)(k0 + 16)*N + j], p2);
    p3 = fmaf(x[k0 + 24], W[(long)(k0 + 24)*N + j], p3);
  }
  part[tk][tx] = (p0+p1)+(p2+p3);
  __syncthreads();
  if (tid < 32){
    float s = part[0][tid];
    #pragma unroll
    for (int q = 1; q < 8; ++q) s += part[q][tid];
    s += bias[col0 + tid];
    out[b*N + col0 + tid] = act ? LKY(s) : s;
  }
}

// ---------------------------------------------------------------------------
// 256x256 matmul C = X @ Y, split-K: block = row; 256 thr = 64 j4-groups x 4 kslc.
// Optional fp32 out + split planes ((k>>3)*256+n)*8+(k&7).
// ---------------------------------------------------------------------------
__global__ __launch_bounds__(256) void matmul_g(
    const float* __restrict__ X, const float* __restrict__ Y,
    float* __restrict__ Cf, ushort_t* __restrict__ Ch, ushort_t* __restrict__ Cl)
{
  int i = blockIdx.x;
  int tid = threadIdx.x;
  int jg = tid & 63, tk = tid >> 6;
  __shared__ float row[256];
  __shared__ float4 part[4][64];
  if (tid < 256) row[tid] = X[i*256 + tid];
  __syncthreads();
  int j4 = jg*4;
  float4 p0 = make_float4(0,0,0,0), p1 = make_float4(0,0,0,0);
  int kb = tk*64;
  #pragma unroll 4
  for (int k = kb; k < kb+64; k += 2){
    float x0 = row[k], x1 = row[k+1];
    float4 y0 = *(const float4*)&Y[(k  )*256 + j4];
    float4 y1 = *(const float4*)&Y[(k+1)*256 + j4];
    p0.x = fmaf(x0,y0.x,p0.x); p0.y = fmaf(x0,y0.y,p0.y);
    p0.z = fmaf(x0,y0.z,p0.z); p0.w = fmaf(x0,y0.w,p0.w);
    p1.x = fmaf(x1,y1.x,p1.x); p1.y = fmaf(x1,y1.y,p1.y);
    p1.z = fmaf(x1,y1.z,p1.z); p1.w = fmaf(x1,y1.w,p1.w);
  }
  p0.x+=p1.x; p0.y+=p1.y; p0.z+=p1.z; p0.w+=p1.w;
  part[tk][jg] = p0;
  __syncthreads();
  if (tid < 64){
    float4 s = part[0][tid];
    #pragma unroll
    for (int q = 1; q < 4; ++q){
      float4 v = part[q][tid];
      s.x+=v.x; s.y+=v.y; s.z+=v.z; s.w+=v.w;
    }
    int j = tid*4;
    if (Cf) *(float4*)&Cf[i*256 + j] = s;
    if (Ch){
      float vv[4] = {s.x,s.y,s.z,s.w};
      #pragma unroll
      for (int e = 0; e < 4; ++e){
        ushort_t h = f2bf(vv[e]);
        int o = ((i>>3)*256 + j + e)*8 + (i&7);
        Ch[o] = h; Cl[o] = f2bf(vv[e] - bf2f(h));
      }
    }
  }
}

// ---------------------------------------------------------------------------
// Split fp32 weight matrix (KxN) into hi/lo bf16 planes in fragment order.
// ---------------------------------------------------------------------------
__global__ __launch_bounds__(256) void prep_w(
    const float* __restrict__ W, ushort_t* __restrict__ Wh,
    ushort_t* __restrict__ Wl, int N)
{
  int o = blockIdx.x*256 + threadIdx.x;
  int j = o & 7;
  int rest = o >> 3;
  int n = rest % N;
  int t8 = rest / N;
  int k = t8*8 + j;
  float v = W[k*N + n];
  ushort_t h = f2bf(v);
  Wh[o] = h;
  Wl[o] = f2bf(v - bf2f(h));
}

// ---------------------------------------------------------------------------
// B_w^T plane for the scan's u-term: K padded 16->32 (zeros), N=256.
// ---------------------------------------------------------------------------
__global__ __launch_bounds__(256) void prep_bw(
    const float* __restrict__ B, ushort_t* __restrict__ Bh, ushort_t* __restrict__ Bl)
{
  int o = blockIdx.x*256 + threadIdx.x;     // 8192 total
  int j = o & 7, rest = o >> 3;
  int n = rest & 255, kq = rest >> 8;
  int k = kq*8 + j;
  float v = (k < ALa) ? B[k*256 + n] : 0.f;
  ushort_t h = f2bf(v);
  Bh[o] = h; Bl[o] = f2bf(v - bf2f(h));
}

// ---------------------------------------------------------------------------
// MFMA chunk scan (zero-init pass). Unchanged from round 4 (known-good).
// ---------------------------------------------------------------------------
__device__ __forceinline__ void load_afrag(
    const ushort_t* __restrict__ P, int kq, int m0, short8* dst)
{
  #pragma unroll
  for (int mt = 0; mt < 4; ++mt)
    dst[mt] = *(const short8*)&P[((long)kq*256 + m0 + mt*16)*8];
}

__global__ __launch_bounds__(256) void scan_mfma(
    const float* __restrict__ in0,
    const ushort_t* __restrict__ AtH, const ushort_t* __restrict__ AtL,
    const ushort_t* __restrict__ BtH, const ushort_t* __restrict__ BtL,
    float* __restrict__ wend, float* __restrict__ zout)
{
  int chunk = blockIdx.x;
  int tid = threadIdx.x;
  int wave = tid >> 6, lane = tid & 63;
  int quad = lane >> 4, l16 = lane & 15;
  int mwave = wave * 64;
  int m0 = mwave + l16;

  __shared__ ushort_t StH[16384];
  __shared__ ushort_t StL[16384];

  short8 Bfh[4], Bfl[4];
  #pragma unroll
  for (int mt = 0; mt < 4; ++mt){
    int off = ((quad)*256 + m0 + mt*16)*8;
    Bfh[mt] = *(const short8*)&BtH[off];
    Bfl[mt] = *(const short8*)&BtL[off];
  }

  f32x4 acc[4][4];
  #pragma unroll
  for (int mt = 0; mt < 4; ++mt)
    #pragma unroll
    for (int nt = 0; nt < 4; ++nt) acc[mt][nt] = (f32x4){0.f,0.f,0.f,0.f};

  const float* ubase[4];
  #pragma unroll
  for (int nt = 0; nt < 4; ++nt)
    ubase[nt] = in0 + (long)(nt*16 + l16)*(Tt*Dd) + (Ss + ALa) + quad*8;

  short8 Ahb[2][4], Alb[2][4];

  for (int tt = 0; tt < CC; ++tt){
    int t = chunk*CC + tt;
    float4 uq[4][2];
    #pragma unroll
    for (int nt = 0; nt < 4; ++nt){
      if (quad < 2){
        const float* up = ubase[nt] + (long)t*Dd;
        uq[nt][0] = *(const float4*)up;
        uq[nt][1] = *(const float4*)(up + 4);
      } else {
        uq[nt][0] = make_float4(0,0,0,0); uq[nt][1] = make_float4(0,0,0,0);
      }
    }

    if (tt > 0){
      load_afrag(AtH, 0*4 + quad, m0, Ahb[0]);
      load_afrag(AtL, 0*4 + quad, m0, Alb[0]);
      #pragma unroll
      for (int kt = 0; kt < 8; ++kt){
        int cur = kt & 1;
        if (kt < 7){
          load_afrag(AtH, (kt+1)*4 + quad, m0, Ahb[cur^1]);
          load_afrag(AtL, (kt+1)*4 + quad, m0, Alb[cur^1]);
        }
        short8 Sbh[4], Sbl[4];
        #pragma unroll
        for (int nt = 0; nt < 4; ++nt){
          int off = ((kt*4 + quad)*64 + nt*16 + l16)*8;
          Sbh[nt] = *(const short8*)&StH[off];
          Sbl[nt] = *(const short8*)&StL[off];
        }
        #pragma unroll
        for (int mt = 0; mt < 4; ++mt)
          #pragma unroll
          for (int nt = 0; nt < 4; ++nt){
            acc[mt][nt] = __builtin_amdgcn_mfma_f32_16x16x32_bf16(Ahb[cur][mt], Sbh[nt], acc[mt][nt], 0,0,0);
            acc[mt][nt] = __builtin_amdgcn_mfma_f32_16x16x32_bf16(Ahb[cur][mt], Sbl[nt], acc[mt][nt], 0,0,0);
            acc[mt][nt] = __builtin_amdgcn_mfma_f32_16x16x32_bf16(Alb[cur][mt], Sbh[nt], acc[mt][nt], 0,0,0);
          }
      }
    }

    short8 uh[4], ul[4];
    #pragma unroll
    for (int nt = 0; nt < 4; ++nt){
      float v[8] = {uq[nt][0].x,uq[nt][0].y,uq[nt][0].z,uq[nt][0].w,
                    uq[nt][1].x,uq[nt][1].y,uq[nt][1].z,uq[nt][1].w};
      ushort_t hs[8], ls[8];
      #pragma unroll
      for (int j = 0; j < 8; ++j){
        hs[j] = f2bf(v[j]);
        ls[j] = f2bf(v[j] - bf2f(hs[j]));
      }
      uh[nt] = *(const short8*)hs; ul[nt] = *(const short8*)ls;
    }
    #pragma unroll
    for (int mt = 0; mt < 4; ++mt)
      #pragma unroll
      for (int nt = 0; nt < 4; ++nt){
        acc[mt][nt] = __builtin_amdgcn_mfma_f32_16x16x32_bf16(Bfh[mt], uh[nt], acc[mt][nt], 0,0,0);
        acc[mt][nt] = __builtin_amdgcn_mfma_f32_16x16x32_bf16(Bfh[mt], ul[nt], acc[mt][nt], 0,0,0);
        acc[mt][nt] = __builtin_amdgcn_mfma_f32_16x16x32_bf16(Bfl[mt], uh[nt], acc[mt][nt], 0,0,0);
      }

    __syncthreads();

    #pragma unroll
    for (int mt = 0; mt < 4; ++mt){
      int mb = mwave + mt*16 + quad*4;
      #pragma unroll
      for (int nt = 0; nt < 4; ++nt){
        int n = nt*16 + l16;
        f32x4 v = acc[mt][nt];
        *(float4*)&zout[((long)n*Tt + t)*Ll + mb] = make_float4(v[0],v[1],v[2],v[3]);
        if (tt == CC-1)
          *(float4*)&wend[((long)chunk*Bb + n)*Ll + mb] = make_float4(v[0],v[1],v[2],v[3]);
        #pragma unroll
        for (int reg = 0; reg < 4; ++reg){
          int m = mb + reg;
          ushort_t h = f2bf(v[reg]);
          ushort_t l = f2bf(v[reg] - bf2f(h));
          int so = ((m>>3)*64 + n)*8 + (m&7);
          StH[so] = h; StL[so] = l;
        }
        acc[mt][nt] = (f32x4){0.f,0.f,0.f,0.f};
      }
    }
    __syncthreads();
  }
}

// ---------------------------------------------------------------------------
// pass2a/b/c: hierarchical boundary recurrence (fp32) — unchanged.
// ---------------------------------------------------------------------------
__global__ __launch_bounds__(256) void pass2_local(
    const float* __restrict__ A8, const float* __restrict__ wend,
    float* __restrict__ lend)
{
  int s = blockIdx.x, rg = blockIdx.y;
  int r = threadIdx.x >> 6, cg = threadIdx.x & 63;
  int b = rg*4 + r;
  __shared__ float cur[4][260];
  float4 l = *(const float4*)&wend[(((SC*s)*Bb) + b)*256 + cg*4];
  *(float4*)&cur[r][cg*4] = l;
  __syncthreads();
  for (int i = 1; i < SC; ++i){
    float4 acc = *(const float4*)&wend[(((SC*s+i)*Bb) + b)*256 + cg*4];
    #pragma unroll 4
    for (int k = 0; k < 256; ++k){
      float lv = cur[r][k];
      float4 a = *(const float4*)&A8[k*256 + cg*4];
      acc.x = fmaf(lv, a.x, acc.x); acc.y = fmaf(lv, a.y, acc.y);
      acc.z = fmaf(lv, a.z, acc.z); acc.w = fmaf(lv, a.w, acc.w);
    }
    __syncthreads();
    *(float4*)&cur[r][cg*4] = acc;
    l = acc;
    __syncthreads();
  }
  *(float4*)&lend[((s*Bb) + b)*256 + cg*4] = l;
}

__global__ __launch_bounds__(256) void pass2_global(
    const float* __restrict__ A64, const float* __restrict__ lend,
    float* __restrict__ inits)
{
  int b = blockIdx.x, tid = threadIdx.x;
  __shared__ float cur[256];
  cur[tid] = inits[b*256 + tid];
  __syncthreads();
  for (int s = 0; s < NSC-1; ++s){
    float p[8] = {0,0,0,0,0,0,0,0};
    #pragma unroll 4
    for (int k = 0; k < 256; k += 8){
      #pragma unroll
      for (int q = 0; q < 8; ++q)
        p[q] = fmaf(cur[k+q], A64[(k+q)*256 + tid], p[q]);
    }
    float acc = lend[((s*Bb) + b)*256 + tid]
              + (((p[0]+p[1])+(p[2]+p[3])) + ((p[4]+p[5])+(p[6]+p[7])));
    __syncthreads();
    cur[tid] = acc;
    inits[((long)((s+1)*SC)*Bb + b)*256 + tid] = acc;
    __syncthreads();
  }
}

__global__ __launch_bounds__(256) void pass2_replay(
    const float* __restrict__ A8, const float* __restrict__ wend,
    float* __restrict__ inits)
{
  int s = blockIdx.x, rg = blockIdx.y;
  int r = threadIdx.x >> 6, cg = threadIdx.x & 63;
  int b = rg*4 + r;
  __shared__ float cur[4][260];
  float4 g = *(const float4*)&inits[(((SC*s)*Bb) + b)*256 + cg*4];
  *(float4*)&cur[r][cg*4] = g;
  __syncthreads();
  for (int i = 0; i < SC-1; ++i){
    float4 acc = *(const float4*)&wend[(((SC*s+i)*Bb) + b)*256 + cg*4];
    #pragma unroll 4
    for (int k = 0; k < 256; ++k){
      float lv = cur[r][k];
      float4 a = *(const float4*)&A8[k*256 + cg*4];
      acc.x = fmaf(lv, a.x, acc.x); acc.y = fmaf(lv, a.y, acc.y);
      acc.z = fmaf(lv, a.z, acc.z); acc.w = fmaf(lv, a.w, acc.w);
    }
    __syncthreads();
    *(float4*)&cur[r][cg*4] = acc;
    *(float4*)&inits[(((SC*s+i+1)*Bb) + b)*256 + cg*4] = acc;
    __syncthreads();
  }
}

// ---------------------------------------------------------------------------
// Correction GEMMs: out[b, c*CC+j, :] += inits[c*64+b] @ A^(j+1). Unchanged.
// ---------------------------------------------------------------------------
__global__ __launch_bounds__(256) void gemm_corr(
    const float* __restrict__ inits, const ushort_t* __restrict__ AjH,
    const ushort_t* __restrict__ AjL, float* __restrict__ out)
{
  int jz = blockIdx.z;
  const ushort_t* Whp = AjH + (long)jz*65536;
  const ushort_t* Wlp = AjL + (long)jz*65536;
  __shared__ __align__(16) ushort_t Xh[4*128*8], Xl[4*128*8];
  __shared__ __align__(16) ushort_t Wh[4*128*8], Wl[4*128*8];

  int tid  = threadIdx.x;
  int wave = tid >> 6, lane = tid & 63;
  int wm = wave & 1, wn = wave >> 1;
  int quad = lane >> 4, l16 = lane & 15;
  int row0 = blockIdx.y * 128;
  int col0 = blockIdx.x * 128;

  f32x4 acc[4][4];
  #pragma unroll
  for (int mt = 0; mt < 4; ++mt)
    #pragma unroll
    for (int nt = 0; nt < 4; ++nt) acc[mt][nt] = (f32x4){0.f,0.f,0.f,0.f};

  for (int kt = 0; kt < 8; ++kt){
    #pragma unroll
    for (int it = 0; it < 2; ++it){
      int idx = tid + it*256;
      int q = idx >> 7, m = idx & 127;
      const float* xp = &inits[(long)(row0 + m)*256 + kt*32 + q*8];
      float4 v0 = *(const float4*)xp;
      float4 v1 = *(const float4*)(xp + 4);
      float vv[8] = {v0.x,v0.y,v0.z,v0.w,v1.x,v1.y,v1.z,v1.w};
      ushort_t hs[8], ls[8];
      #pragma unroll
      for (int j = 0; j < 8; ++j){
        hs[j] = f2bf(vv[j]);
        ls[j] = f2bf(vv[j] - bf2f(hs[j]));
      }
      *(uint4*)&Xh[(q*128 + m)*8] = *(const uint4*)hs;
      *(uint4*)&Xl[(q*128 + m)*8] = *(const uint4*)ls;
      int n = idx & 127;
      long src = (long)(kt*4 + q)*256 + col0 + n;
      ((uint4*)Wh)[q*128 + n] = ((const uint4*)Whp)[src];
      ((uint4*)Wl)[q*128 + n] = ((const uint4*)Wlp)[src];
    }
    __syncthreads();
    short8 ah[4], al[4], bh[4], bl[4];
    #pragma unroll
    for (int mt = 0; mt < 4; ++mt){
      int off = (quad*128 + wm*64 + mt*16 + l16)*8;
      ah[mt] = *(const short8*)&Xh[off];
      al[mt] = *(const short8*)&Xl[off];
    }
    #pragma unroll
    for (int nt = 0; nt < 4; ++nt){
      int off = (quad*128 + wn*64 + nt*16 + l16)*8;
      bh[nt] = *(const short8*)&Wh[off];
      bl[nt] = *(const short8*)&Wl[off];
    }
    #pragma unroll
    for (int mt = 0; mt < 4; ++mt)
      #pragma unroll
      for (int nt = 0; nt < 4; ++nt){
        acc[mt][nt] = __builtin_amdgcn_mfma_f32_16x16x32_bf16(ah[mt], bh[nt], acc[mt][nt], 0,0,0);
        acc[mt][nt] = __builtin_amdgcn_mfma_f32_16x16x32_bf16(ah[mt], bl[nt], acc[mt][nt], 0,0,0);
        acc[mt][nt] = __builtin_amdgcn_mfma_f32_16x16x32_bf16(al[mt], bh[nt], acc[mt][nt], 0,0,0);
      }
    __syncthreads();
  }

  #pragma unroll
  for (int mt = 0; mt < 4; ++mt){
    #pragma unroll
    for (int nt = 0; nt < 4; ++nt){
      int col = col0 + wn*64 + nt*16 + l16;
      #pragma unroll
      for (int reg = 0; reg < 4; ++reg){
        int row = row0 + wm*64 + mt*16 + quad*4 + reg;
        int b = row & 63, c = row >> 6;
        int t = c*CC + jz;
        long addr = ((long)b*Tt + t)*Ll + col;
        out[addr] += acc[mt][nt][reg];
      }
    }
  }
}

// ---------------------------------------------------------------------------
// Decoder split-bf16 MFMA GEMM (template unchanged; launched at 64x128 now).
// ---------------------------------------------------------------------------
template<int BM, int BN, bool INS, bool OUTS>
__global__ __launch_bounds__(256) void gemm_mfma(
    const float* __restrict__ X,
    const ushort_t* __restrict__ Xhp, const ushort_t* __restrict__ Xlp,
    const ushort_t* __restrict__ Whp, const ushort_t* __restrict__ Wlp,
    const float* __restrict__ bias, float* __restrict__ Y,
    ushort_t* __restrict__ Yh, ushort_t* __restrict__ Yl,
    int Mrows, int K, int N, int act)
{
  constexpr int BMh = BM/2, BNh = BN/2;
  constexpr int MT = BM/32, NT = BN/32;
  __shared__ __align__(16) ushort_t Xh[4*BM*8], Xl[4*BM*8];
  __shared__ __align__(16) ushort_t Wh[4*BN*8], Wl[4*BN*8];

  int tid  = threadIdx.x;
  int wave = tid >> 6, lane = tid & 63;
  int wm = wave & 1, wn = wave >> 1;
  int quad = lane >> 4, l16 = lane & 15;
  long row0 = (long)blockIdx.y * BM;
  int col0 = blockIdx.x * BN;

  f32x4 acc[MT][NT];
  #pragma unroll
  for (int mt = 0; mt < MT; ++mt)
    #pragma unroll
    for (int nt = 0; nt < NT; ++nt) acc[mt][nt] = (f32x4){0.f,0.f,0.f,0.f};

  for (int kt = 0; kt < K; kt += 32){
    int ktile = kt >> 5;
    if constexpr (INS){
      #pragma unroll
      for (int it = 0; it < (BM*4)/256; ++it){
        int idx = tid + it*256;
        int q = idx / BM, m = idx % BM;
        long src = (long)(ktile*4 + q)*Mrows + row0 + m;
        ((uint4*)Xh)[q*BM + m] = ((const uint4*)Xhp)[src];
        ((uint4*)Xl)[q*BM + m] = ((const uint4*)Xlp)[src];
      }
    } else {
      #pragma unroll
      for (int it = 0; it < (BM*4)/256; ++it){
        int idx = tid + it*256;
        int q = idx / BM, m = idx % BM;
        const float* xp = &X[(row0 + m)*(long)K + kt + q*8];
        float4 v0 = *(const float4*)xp;
        float4 v1 = *(const float4*)(xp + 4);
        float vv[8] = {v0.x,v0.y,v0.z,v0.w,v1.x,v1.y,v1.z,v1.w};
        ushort_t hs[8], ls[8];
        #pragma unroll
        for (int j = 0; j < 8; ++j){
          hs[j] = f2bf(vv[j]);
          ls[j] = f2bf(vv[j] - bf2f(hs[j]));
        }
        *(uint4*)&Xh[(q*BM + m)*8] = *(const uint4*)hs;
        *(uint4*)&Xl[(q*BM + m)*8] = *(const uint4*)ls;
      }
    }
    #pragma unroll
    for (int it = 0; it < (BN*4)/256; ++it){
      int idx = tid + it*256;
      int q = idx / BN, n = idx % BN;
      long src = (long)(ktile*4 + q)*N + col0 + n;
      ((uint4*)Wh)[q*BN + n] = ((const uint4*)Whp)[src];
      ((uint4*)Wl)[q*BN + n] = ((const uint4*)Wlp)[src];
    }
    __syncthreads();

    short8 ah[MT], al[MT], bh[NT], bl[NT];
    #pragma unroll
    for (int mt = 0; mt < MT; ++mt){
      int off = (quad*BM + wm*BMh + mt*16 + l16)*8;
      ah[mt] = *(const short8*)&Xh[off];
      al[mt] = *(const short8*)&Xl[off];
    }
    #pragma unroll
    for (int nt = 0; nt < NT; ++nt){
      int off = (quad*BN + wn*BNh + nt*16 + l16)*8;
      bh[nt] = *(const short8*)&Wh[off];
      bl[nt] = *(const short8*)&Wl[off];
    }
    #pragma unroll
    for (int mt = 0; mt < MT; ++mt)
      #pragma unroll
      for (int nt = 0; nt < NT; ++nt){
        acc[mt][nt] = __builtin_amdgcn_mfma_f32_16x16x32_bf16(ah[mt], bh[nt], acc[mt][nt], 0, 0, 0);
        acc[mt][nt] = __builtin_amdgcn_mfma_f32_16x16x32_bf16(ah[mt], bl[nt], acc[mt][nt], 0, 0, 0);
        acc[mt][nt] = __builtin_amdgcn_mfma_f32_16x16x32_bf16(al[mt], bh[nt], acc[mt][nt], 0, 0, 0);
      }
    __syncthreads();
  }

  #pragma unroll
  for (int mt = 0; mt < MT; ++mt){
    long rowb = row0 + wm*BMh + mt*16 + quad*4;
    #pragma unroll
    for (int nt = 0; nt < NT; ++nt){
      int col = col0 + wn*BNh + nt*16 + l16;
      float bs = bias[col];
      #pragma unroll
      for (int reg = 0; reg < 4; ++reg){
        float y = acc[mt][nt][reg] + bs;
        if (act) y = LKY(y);
        long row = rowb + reg;
        if constexpr (OUTS){
          ushort_t h = f2bf(y);
          ushort_t l = f2bf(y - bf2f(h));
          long off = ((long)(col >> 3)*Mrows + row)*8 + (col & 7);
          Yh[off] = h; Yl[off] = l;
        } else {
          Y[row*(long)N + col] = y;
        }
      }
    }
  }
}

// ---------------------------------------------------------------------------
extern "C" void kernel_launch(void* const* d_in, const int* in_sizes, int n_in,
                              void* d_out, int out_size, void* d_ws, size_t ws_size,
                              hipStream_t stream) {
  const float* in0    = (const float*)d_in[0];
  const float* enc_w1 = (const float*)d_in[1];
  const float* enc_b1 = (const float*)d_in[2];
  const float* enc_w2 = (const float*)d_in[3];
  const float* enc_b2 = (const float*)d_in[4];
  const float* enc_w3 = (const float*)d_in[5];
  const float* enc_b3 = (const float*)d_in[6];
  const float* A_w    = (const float*)d_in[7];
  const float* B_w    = (const float*)d_in[8];
  const float* dec_w1 = (const float*)d_in[9];
  const float* dec_b1 = (const float*)d_in[10];
  const float* dec_w2 = (const float*)d_in[11];
  const float* dec_b2 = (const float*)d_in[12];
  const float* dec_w3 = (const float*)d_in[13];
  const float* dec_b3 = (const float*)d_in[14];
  float* out = (float*)d_out;

  // ---- workspace layout (float slots); total 9,437,184 fl = 37.75 MB ----
  float* ws    = (float*)d_ws;
  float* h1enc = ws;                      // 32768
  float* h2enc = ws + 32768;              // 32768
  float* s2    = ws + 65536;              // A^2
  float* s3    = ws + 131072;             // A^3
  float* s4    = ws + 196608;             // A^4
  float* s8    = ws + 262144;             // A^8 (pass2)
  float* s16   = ws + 327680;
  float* s32   = ws + 393216;
  float* s64   = ws + 458752;             // A^64 (pass2b)
  ushort_t* Whp_d = (ushort_t*)(ws + 524288);   // decoder W planes
  ushort_t* Wlp_d = (ushort_t*)(ws + 786432);
  float* Rf    = ws + 1048576;            // R-pool: 8,388,608 fl
  // scan-phase layout of R:
  ushort_t* AjH = (ushort_t*)Rf;                // 8 planes x 65536 ush
  ushort_t* AjL = (ushort_t*)(Rf + 262144);
  ushort_t* BtH = (ushort_t*)(Rf + 524288);     // 8192 ush
  ushort_t* BtL = BtH + 8192;
  float* wend  = Rf + 532480;             // 2,097,152
  float* inits = Rf + 2629632;            // 2,097,152 (inits[0] = z0)
  float* lend  = Rf + 4726784;            // 262,144
  // decoder-phase aliases of R (scan data dead by then):
  ushort_t* h1h = (ushort_t*)Rf;
  ushort_t* h1l = (ushort_t*)(Rf + 2097152);
  ushort_t* h2h = (ushort_t*)(Rf + 4194304);
  ushort_t* h2l = (ushort_t*)(Rf + 6291456);

  // Encoder (only t=0 feeds the scan) -> z0 into inits[0]
  enc_dense<<<dim3(64,16), 256, 0, stream>>>(in0, Tt*Dd, enc_w1, enc_b1, h1enc, 256, 512, 1);
  enc_dense<<<dim3(64,16), 256, 0, stream>>>(h1enc, 512, enc_w2, enc_b2, h2enc, 512, 512, 1);
  enc_dense<<<dim3(64, 8), 256, 0, stream>>>(h2enc, 512, enc_w3, enc_b3, inits, 512, 256, 1);

  // A^j planes (j=1..8) + fp32 A^8 / A^64 for pass2
  prep_w<<<256, 256, 0, stream>>>(A_w, AjH, AjL, 256);                       // A^1 plane
  prep_bw<<<32, 256, 0, stream>>>(B_w, BtH, BtL);
  matmul_g<<<256, 256, 0, stream>>>(A_w, A_w, s2, AjH+1*65536, AjL+1*65536); // A^2
  matmul_g<<<256, 256, 0, stream>>>(s2, A_w, s3, AjH+2*65536, AjL+2*65536);  // A^3
  matmul_g<<<256, 256, 0, stream>>>(s2, s2, s4, AjH+3*65536, AjL+3*65536);   // A^4
  matmul_g<<<256, 256, 0, stream>>>(s4, A_w, nullptr, AjH+4*65536, AjL+4*65536); // A^5
  matmul_g<<<256, 256, 0, stream>>>(s4, s2, nullptr, AjH+5*65536, AjL+5*65536);  // A^6
  matmul_g<<<256, 256, 0, stream>>>(s4, s3, nullptr, AjH+6*65536, AjL+6*65536);  // A^7
  matmul_g<<<256, 256, 0, stream>>>(s4, s4, s8, AjH+7*65536, AjL+7*65536);   // A^8
  matmul_g<<<256, 256, 0, stream>>>(s8, s8, s16, nullptr, nullptr);          // A^16
  matmul_g<<<256, 256, 0, stream>>>(s16, s16, s32, nullptr, nullptr);        // A^32
  matmul_g<<<256, 256, 0, stream>>>(s32, s32, s64, nullptr, nullptr);        // A^64

  // Decoder weight planes
  prep_w<<<512,  256, 0, stream>>>(dec_w1, Whp_d,          Wlp_d,          512);
  prep_w<<<1024, 256, 0, stream>>>(dec_w2, Whp_d + 131072, Wlp_d + 131072, 512);
  prep_w<<<512,  256, 0, stream>>>(dec_w3, Whp_d + 393216, Wlp_d + 393216, 256);

  // Pass 1: MFMA zero-init chunk scans; w[t] -> d_out, ends -> wend
  scan_mfma<<<NCh, 256, 0, stream>>>(in0, AjH, AjL, BtH, BtL, wend, out);
  // Pass 2: hierarchical boundary recurrence (fp32, depth 7+15+7)
  pass2_local <<<dim3(NSC, 16), 256, 0, stream>>>(s8, wend, lend);
  pass2_global<<<64,            256, 0, stream>>>(s64, lend, inits);
  pass2_replay<<<dim3(NSC, 16), 256, 0, stream>>>(s8, wend, inits);
  // Pass 3 (parallel corrections): out[b, c*8+j, :] += inits[c] @ A^(j+1)
  gemm_corr<<<dim3(2, 64, 8), 256, 0, stream>>>(inits, AjH, AjL, out);

  // Decoder: 3-layer MLP, split-bf16 MFMA, 64x128 tiles (2 blocks/CU)
  for (int rc = 0; rc < DEC_CHUNKS; ++rc){
    const float* zc = out + (long)rc*DEC_ROWS*Ll;
    float* oc       = out + (long)rc*DEC_ROWS*Ll;
    gemm_mfma<64,128,false,true><<<dim3(Ee/128, DEC_ROWS/64), 256, 0, stream>>>(
        zc, nullptr, nullptr, Whp_d, Wlp_d, dec_b1, nullptr, h1h, h1l, DEC_ROWS, Ll, Ee, 1);
    gemm_mfma<64,128,true,true><<<dim3(Ee/128, DEC_ROWS/64), 256, 0, stream>>>(
        nullptr, h1h, h1l, Whp_d + 131072, Wlp_d + 131072, dec_b2, nullptr, h2h, h2l, DEC_ROWS, Ee, Ee, 1);
    gemm_mfma<64,128,true,false><<<dim3(Ss/128, DEC_ROWS/64), 256, 0, stream>>>(
        nullptr, h2h, h2l, Whp_d + 393216, Wlp_d + 393216, dec_b3, oc, nullptr, nullptr, DEC_ROWS, Ee, Ss, 0);
  }
}